// Round 13
// baseline (1048.584 us; speedup 1.0000x reference)
//
#include <hip/hip_runtime.h>
#include <hip/hip_bf16.h>

#define T_LEN 1024
#define CDIM  768
#define HNUM  12
#define KDIM  64
#define LNUM  6
#define FDIM  2688
#define VDIM  50304
#define NCH   16     // wkv chunks
#define LCH   64     // chunk length

#define WSZ   (CDIM * CDIM)              // 589824
#define WIN_OFF  (6 * WSZ)               // 3538944
#define WOUT_OFF (WIN_OFF + CDIM * FDIM) // 5603328
#define WBUF_ELEMS (WOUT_OFF + FDIM * CDIM)  // 7667712 elems per layer

typedef __attribute__((ext_vector_type(4))) float f32x4;
typedef __attribute__((ext_vector_type(8))) short s16x8;

__device__ __forceinline__ ushort f2bf(float f) {
    union { float fv; unsigned u; } v; v.fv = f;
    unsigned r = v.u + 0x7fffu + ((v.u >> 16) & 1u);   // RNE
    return (ushort)(r >> 16);
}

__device__ __forceinline__ void gload_lds16(const ushort* g, ushort* l) {
    __builtin_amdgcn_global_load_lds(
        (const __attribute__((address_space(1))) void*)g,
        (__attribute__((address_space(3))) void*)l, 16, 0, 0);
}

template <int N_>
__device__ __forceinline__ void wait_vm() {
    if constexpr (N_ == 0)       asm volatile("s_waitcnt vmcnt(0)" ::: "memory");
    else if constexpr (N_ == 8)  asm volatile("s_waitcnt vmcnt(8)" ::: "memory");
    else                         asm volatile("s_waitcnt vmcnt(16)" ::: "memory");
}
__device__ __forceinline__ void barrier_asm() {
    asm volatile("s_barrier" ::: "memory");
}

// ---- fragment-order store index for B^T[n][k] of a KxN weight (K=R rows) ---
// chunk (n16,k64,s)=1KB: lane l = kq*16+ln15 holds B^T[n16*16+ln15][k64*64+s*32+kq*8+e]
__device__ __forceinline__ size_t frag_idx(int nn, int k, int K) {
    int n16 = nn >> 4, ln15 = nn & 15;
    int k64 = k >> 6, s = (k >> 5) & 1, kq = (k >> 3) & 3;
    return ((size_t)(n16 * (K >> 6) + k64) * 2 + s) * 512 + (kq * 16 + ln15) * 8
           + (k & 4);
}

// -------- REGISTER-transpose quad: 128x128 region, zero LDS, no barrier -----
__device__ __forceinline__ void trans_quad_reg(const float* __restrict__ in,
        ushort* __restrict__ out, int R, int C, int tkq, int tnp) {
    int tid = threadIdx.x;
    int k4 = tid >> 4, n4 = tid & 15;
    int kb = (tkq << 7) + k4 * 4;
    int nb = (tnp << 7) + n4 * 4;
    float4 v[2][2][4];
    #pragma unroll
    for (int dk = 0; dk < 2; dk++)
        #pragma unroll
        for (int dn = 0; dn < 2; dn++)
            #pragma unroll
            for (int j = 0; j < 4; j++)
                v[dk][dn][j] = *(const float4*)
                    &in[(size_t)(kb + dk * 64 + j) * C + nb + dn * 64];
    #pragma unroll
    for (int dk = 0; dk < 2; dk++)
        #pragma unroll
        for (int dn = 0; dn < 2; dn++) {
            const float* f0 = (const float*)&v[dk][dn][0];
            const float* f1 = (const float*)&v[dk][dn][1];
            const float* f2 = (const float*)&v[dk][dn][2];
            const float* f3 = (const float*)&v[dk][dn][3];
            #pragma unroll
            for (int e = 0; e < 4; e++) {
                ushort4 u;
                u.x = f2bf(f0[e]); u.y = f2bf(f1[e]);
                u.z = f2bf(f2[e]); u.w = f2bf(f3[e]);
                *(ushort4*)&out[frag_idx(nb + dn * 64 + e, kb + dk * 64, R)] = u;
            }
        }
}

// single-tile LDS variant (fallback path only)
__device__ __forceinline__ void trans_tile(const float* __restrict__ in,
        ushort* __restrict__ out, int R, int C, int tk, int tn) {
    __shared__ float tile[64][65];
    int tid = threadIdx.x;
    int r = tid >> 4, c4 = (tid & 15) << 2;
    int k0 = tk << 6, n0 = tn << 6;
    #pragma unroll
    for (int j = 0; j < 4; j++) {
        int rr = r + j * 16;
        float4 f = *(const float4*)&in[(size_t)(k0 + rr) * C + n0 + c4];
        tile[rr][c4 + 0] = f.x; tile[rr][c4 + 1] = f.y;
        tile[rr][c4 + 2] = f.z; tile[rr][c4 + 3] = f.w;
    }
    __syncthreads();
    #pragma unroll
    for (int j = 0; j < 4; j++) {
        int n = r + j * 16;
        ushort4 u;
        u.x = f2bf(tile[c4 + 0][n]);
        u.y = f2bf(tile[c4 + 1][n]);
        u.z = f2bf(tile[c4 + 2][n]);
        u.w = f2bf(tile[c4 + 3][n]);
        *(ushort4*)&out[frag_idx(n0 + n, k0 + c4, R)] = u;
    }
}

__global__ __launch_bounds__(256)
void k_trans(const float* __restrict__ in, ushort* __restrict__ out, int R, int C) {
    trans_tile(in, out, R, C, blockIdx.y, blockIdx.x);
}

// ---------------- embed lookup + LN row (device func, also standalone) ------
__device__ __forceinline__ void embed_ln_row(int t, const int* __restrict__ tok,
        const float* __restrict__ embed, const float* __restrict__ wb,
        float* __restrict__ xout) {
    int tid = threadIdx.x;
    const float* row = embed + (size_t)tok[t] * CDIM;
    float v[3]; float s = 0.f, s2 = 0.f;
    #pragma unroll
    for (int j = 0; j < 3; j++) {
        v[j] = row[tid + j * 256]; s += v[j]; s2 += v[j] * v[j];
    }
    #pragma unroll
    for (int m = 32; m; m >>= 1) { s += __shfl_xor(s, m); s2 += __shfl_xor(s2, m); }
    __shared__ float rs[4], rq[4];
    int w = tid >> 6;
    if ((tid & 63) == 0) { rs[w] = s; rq[w] = s2; }
    __syncthreads();
    s = rs[0] + rs[1] + rs[2] + rs[3];
    s2 = rq[0] + rq[1] + rq[2] + rq[3];
    float mu = s * (1.f / CDIM);
    float inv = rsqrtf(s2 * (1.f / CDIM) - mu * mu + 1e-5f);
    #pragma unroll
    for (int j = 0; j < 3; j++) {
        int c = tid + j * 256;
        xout[(size_t)t * CDIM + c] = (v[j] - mu) * inv * wb[c] + wb[CDIM + c];
    }
}

__global__ __launch_bounds__(256)
void k_embed_ln(const int* __restrict__ tok, const float* __restrict__ embed,
                const float* __restrict__ wb, float* __restrict__ xout) {
    embed_ln_row(blockIdx.x, tok, embed, wb, xout);
}

// per-layer QUAD tile mapping: 468 quads per layer
__device__ __forceinline__ void conv_layer_quad(int t,
        const float* p0, const float* p1, const float* p2, const float* p3,
        const float* p4, const float* p5, const float* pWin, const float* pWout,
        ushort* wl) {
    const float* in; ushort* out; int R, C, tkq, tnp;
    if (t < 216) {                         // 6 square mats, 36 quads each
        int mi = t / 36, tt = t % 36;
        switch (mi) {
            case 0: in = p0; break; case 1: in = p1; break;
            case 2: in = p2; break; case 3: in = p3; break;
            case 4: in = p4; break; default: in = p5; break;
        }
        out = wl + (size_t)mi * WSZ; R = 768; C = 768;
        tkq = tt / 6; tnp = tt % 6;
    } else if (t < 342) {                  // Win: 6 tkq x 21 tnp
        int tt = t - 216;
        in = pWin; out = wl + WIN_OFF; R = 768; C = 2688;
        tkq = tt / 21; tnp = tt % 21;
    } else {                               // Wout: 21 tkq x 6 tnp
        int tt = t - 342;
        in = pWout; out = wl + WOUT_OFF; R = 2688; C = 768;
        tkq = tt / 6; tnp = tt % 6;
    }
    trans_quad_reg(in, out, R, C, tkq, tnp);
}

// fallback per-layer converter (single tiles; only used if ws too small)
__global__ __launch_bounds__(256)
void k_conv_layer(const float* p0, const float* p1, const float* p2,
                  const float* p3, const float* p4, const float* p5,
                  const float* pWin, const float* pWout, ushort* wl) {
    int t = blockIdx.x;                    // 1872 single tiles
    const float* in; ushort* out; int R, C, tk, tn;
    if (t < 864) {
        int mi = t / 144, tt = t % 144;
        switch (mi) {
            case 0: in = p0; break; case 1: in = p1; break;
            case 2: in = p2; break; case 3: in = p3; break;
            case 4: in = p4; break; default: in = p5; break;
        }
        out = wl + (size_t)mi * WSZ; R = 768; C = 768;
        tk = tt / 12; tn = tt % 12;
    } else if (t < 1368) {
        int tt = t - 864;
        in = pWin; out = wl + WIN_OFF; R = 768; C = 2688;
        tk = tt / 42; tn = tt % 42;
    } else {
        int tt = t - 1368;
        in = pWout; out = wl + WOUT_OFF; R = 2688; C = 768;
        tk = tt / 12; tn = tt % 12;
    }
    trans_tile(in, out, R, C, tk, tn);
}

// all 6 layers + unembed + embed_ln in one launch
__global__ __launch_bounds__(256)
void k_conv_all(const float* Wr, const float* Wk, const float* Wv,
                const float* Wg, const float* Wo, const float* Wcg,
                const float* Win, const float* Wout, const float* unemb,
                ushort* wbuf, ushort* ubuf,
                const int* tok, const float* embed, const float* eln, float* x) {
    int b = blockIdx.x;
    if (b < 6 * 468) {
        int l = b / 468, t = b % 468;
        conv_layer_quad(t,
            Wr + (size_t)l * WSZ, Wk + (size_t)l * WSZ, Wv + (size_t)l * WSZ,
            Wg + (size_t)l * WSZ, Wo + (size_t)l * WSZ, Wcg + (size_t)l * WSZ,
            Win + (size_t)l * CDIM * FDIM, Wout + (size_t)l * FDIM * CDIM,
            wbuf + (size_t)l * WBUF_ELEMS);
    } else if (b < 6 * 468 + 2358) {
        int t = b - 6 * 468;               // unembed: 6 tkq x 393 tnp
        int tkq = t / 393, tnp = t % 393;
        trans_quad_reg(unemb, ubuf, CDIM, VDIM, tkq, tnp);
    } else {
        embed_ln_row(b - (6 * 468 + 2358), tok, embed, eln, x);
    }
}

// ---------------- LayerNorm over C=768 -> bf16 (head input) ----------------
__global__ __launch_bounds__(256)
void k_ln_bf(const float* __restrict__ x, const float* __restrict__ wb,
             ushort* __restrict__ out) {
    int t = blockIdx.x, tid = threadIdx.x;
    float v[3]; float s = 0.f, s2 = 0.f;
    #pragma unroll
    for (int j = 0; j < 3; j++) {
        v[j] = x[(size_t)t * CDIM + tid + j * 256];
        s += v[j]; s2 += v[j] * v[j];
    }
    #pragma unroll
    for (int m = 32; m; m >>= 1) { s += __shfl_xor(s, m); s2 += __shfl_xor(s2, m); }
    __shared__ float rs[4], rq[4];
    int w = tid >> 6;
    if ((tid & 63) == 0) { rs[w] = s; rq[w] = s2; }
    __syncthreads();
    s = rs[0] + rs[1] + rs[2] + rs[3];
    s2 = rq[0] + rq[1] + rq[2] + rq[3];
    float mu = s * (1.f / CDIM);
    float inv = rsqrtf(s2 * (1.f / CDIM) - mu * mu + 1e-5f);
    #pragma unroll
    for (int j = 0; j < 3; j++) {
        int c = tid + j * 256;
        out[(size_t)t * CDIM + c] = f2bf((v[j] - mu) * inv * wb[c] + wb[CDIM + c]);
    }
}

// ---------------- fused LN + token-shift lerp -> NM bf16 mix buffers --------
template <int NM>
__global__ __launch_bounds__(256)
void k_lnlerp(const float* __restrict__ x, const float* __restrict__ lnw,
              const float* __restrict__ ts, ushort* __restrict__ mix) {
    int t = blockIdx.x, tid = threadIdx.x;
    bool has = (t > 0);
    float vb[3], va[3];
    float sb = 0.f, qb = 0.f, sa = 0.f, qa = 0.f;
    #pragma unroll
    for (int j = 0; j < 3; j++) {
        int c = tid + j * 256;
        vb[j] = x[(size_t)t * CDIM + c];
        sb += vb[j]; qb += vb[j] * vb[j];
        va[j] = has ? x[(size_t)(t - 1) * CDIM + c] : 0.f;
        sa += va[j]; qa += va[j] * va[j];
    }
    #pragma unroll
    for (int m = 32; m; m >>= 1) {
        sb += __shfl_xor(sb, m); qb += __shfl_xor(qb, m);
        sa += __shfl_xor(sa, m); qa += __shfl_xor(qa, m);
    }
    __shared__ float r0[4], r1[4], r2[4], r3[4];
    int w = tid >> 6;
    if ((tid & 63) == 0) { r0[w] = sb; r1[w] = qb; r2[w] = sa; r3[w] = qa; }
    __syncthreads();
    sb = r0[0] + r0[1] + r0[2] + r0[3]; qb = r1[0] + r1[1] + r1[2] + r1[3];
    sa = r2[0] + r2[1] + r2[2] + r2[3]; qa = r3[0] + r3[1] + r3[2] + r3[3];
    float mub = sb * (1.f / CDIM);
    float invb = rsqrtf(qb * (1.f / CDIM) - mub * mub + 1e-5f);
    float mua = sa * (1.f / CDIM);
    float inva = rsqrtf(qa * (1.f / CDIM) - mua * mua + 1e-5f);
    #pragma unroll
    for (int j = 0; j < 3; j++) {
        int c = tid + j * 256;
        float wgt = lnw[c], bia = lnw[CDIM + c];
        float xb = (vb[j] - mub) * invb * wgt + bia;
        float xa = has ? (va[j] - mua) * inva * wgt + bia : 0.f;
        #pragma unroll
        for (int m = 0; m < NM; m++) {
            float tv = ts[m * CDIM + c];
            mix[((size_t)m * T_LEN + t) * CDIM + c] = f2bf(xa + (xb - xa) * tv);
        }
    }
}

// ------- layer GEMM: ZERO LDS, ZERO barriers. Both operands fragment-direct -
// A row-major bf16 (frag = contiguous 16B load); B pre-laid in frag order.
// Register double-buffer (named a0/a1/b0/b1); compiler inserts per-reg waits.
// EPI: 0 = f32, 1 = resid+f32, 2 = relu^2 -> bf16, 3 = resid + v*sigmoid(gate)
template <int BM, int BN, int EPI>
__device__ __forceinline__ void gemm_reg(
        const ushort* __restrict__ A, const ushort* __restrict__ Bf,
        float* __restrict__ Cf, ushort* __restrict__ Cb,
        const float* __restrict__ resid, const float* __restrict__ gate,
        int N, int K, int mb, int nb) {
    const int tid = threadIdx.x, lane = tid & 63, wave = tid >> 6;
    constexpr int WM = BM / 2, WN = BN / 2, FM = WM / 16, FN = WN / 16;
    const int wm = (wave >> 1) * WM, wn = (wave & 1) * WN;
    const int kq = lane >> 4, ln15 = lane & 15;
    const size_t bstride = (size_t)(K >> 6) * 1024;   // ushorts per n16 row
    const ushort* abase = A + (size_t)(mb + wm + ln15) * K + kq * 8;
    const ushort* bbase = Bf + (size_t)((nb + wn) >> 4) * bstride + lane * 8;

    auto loadA = [&](s16x8 (&a)[2][FM], int kt) {
        #pragma unroll
        for (int s = 0; s < 2; s++)
            #pragma unroll
            for (int i = 0; i < FM; i++)
                a[s][i] = *(const s16x8*)(abase + (size_t)(i * 16) * K
                                          + kt * 64 + s * 32);
    };
    auto loadB = [&](s16x8 (&b)[2][FN], int kt) {
        #pragma unroll
        for (int s = 0; s < 2; s++)
            #pragma unroll
            for (int j = 0; j < FN; j++)
                b[s][j] = *(const s16x8*)(bbase + (size_t)j * bstride
                                          + (size_t)kt * 1024 + s * 512);
    };

    f32x4 acc[FM][FN];
    #pragma unroll
    for (int i = 0; i < FM; i++)
        #pragma unroll
        for (int j = 0; j < FN; j++) acc[i][j] = (f32x4)0.f;

    auto comp = [&](s16x8 (&a)[2][FM], s16x8 (&b)[2][FN]) {
        #pragma unroll
        for (int s = 0; s < 2; s++)
            #pragma unroll
            for (int i = 0; i < FM; i++)
                #pragma unroll
                for (int j = 0; j < FN; j++)
                    acc[i][j] = __builtin_amdgcn_mfma_f32_16x16x32_bf16(
                        a[s][i], b[s][j], acc[i][j], 0, 0, 0);
    };

    const int nt = K >> 6;               // even (12 or 42) at every call site
    s16x8 a0[2][FM], a1[2][FM], b0[2][FN], b1[2][FN];
    loadA(a0, 0); loadB(b0, 0);
    loadA(a1, 1); loadB(b1, 1);
    for (int t = 0; t < nt; t += 2) {
        comp(a0, b0);
        if (t + 2 < nt) { loadA(a0, t + 2); loadB(b0, t + 2); }
        comp(a1, b1);
        if (t + 3 < nt) { loadA(a1, t + 3); loadB(b1, t + 3); }
    }
    #pragma unroll
    for (int i = 0; i < FM; i++) {
        int rbase = mb + wm + i * 16 + (lane >> 4) * 4;
        #pragma unroll
        for (int j = 0; j < FN; j++) {
            int col = nb + wn + j * 16 + ln15;
            #pragma unroll
            for (int r = 0; r < 4; r++) {
                size_t idx = (size_t)(rbase + r) * N + col;
                float vv = acc[i][j][r];
                if constexpr (EPI == 0) {
                    Cf[idx] = vv;
                } else if constexpr (EPI == 1) {
                    Cf[idx] = resid[idx] + vv;
                } else if constexpr (EPI == 2) {
                    float z = vv > 0.f ? vv * vv : 0.f;
                    Cb[idx] = f2bf(z);
                } else {
                    float gv = gate[idx];
                    Cf[idx] = resid[idx] + vv / (1.f + __expf(-gv));
                }
            }
        }
    }
}

template <int BM, int BN, int EPI, bool BATCH>
__global__ __launch_bounds__(256)
void k_gemm_std(const ushort* __restrict__ A, const ushort* __restrict__ Bf,
                float* __restrict__ Cf, ushort* __restrict__ Cb,
                const float* __restrict__ resid, const float* __restrict__ gate,
                int N, int K) {
    if constexpr (BATCH) {
        int z = blockIdx.z;
        A  += (size_t)z * T_LEN * CDIM;
        Bf += (size_t)z * CDIM * CDIM;
        Cf += (size_t)z * T_LEN * CDIM;
    }
    gemm_reg<BM, BN, EPI>(A, Bf, Cf, Cb, resid, gate, N, K,
                          blockIdx.y * BM, blockIdx.x * BN);
}

// channel-mixer Win (relu^2 -> hb) + Wcg (f32 gcm) merged, 64x64 tiles
__global__ __launch_bounds__(256)
void k_cmix(const ushort* __restrict__ mix, const ushort* __restrict__ wl,
            ushort* __restrict__ hb, float* __restrict__ gcm) {
    int bx = blockIdx.x, mb = blockIdx.y * 64;
    if (bx < FDIM / 64) {
        gemm_reg<64, 64, 2>(mix, wl + WIN_OFF, nullptr, hb, nullptr, nullptr,
                            FDIM, CDIM, mb, bx * 64);
    } else {
        gemm_reg<64, 64, 0>(mix + (size_t)T_LEN * CDIM, wl + 5 * WSZ, gcm,
                            nullptr, nullptr, nullptr, CDIM, CDIM, mb,
                            (bx - FDIM / 64) * 64);
    }
}

// ------- head GEMM: BOTH operands LDS-staged (proven fastest for head) ------
__global__ __launch_bounds__(256)
void k_gemm_head(const ushort* __restrict__ A, const ushort* __restrict__ Bf,
                 float* __restrict__ C) {
    __shared__ __align__(16) ushort Al[2 * 128 * 64];
    __shared__ __align__(16) ushort Bl[2 * 128 * 64];
    int id = blockIdx.x;
    int xcd = id & 7, slot = id >> 3;
    int mbi = slot & 7, nbl = slot >> 3;
    int nbi = nbl * 8 + xcd;                 // bijective, balanced
    if (nbi >= VDIM / 128) return;
    const int mb = mbi * 128, nb = nbi * 128;
    const int tid = threadIdx.x, lane = tid & 63, wave = tid >> 6;
    const int wm = (wave >> 1) * 64, wn = (wave & 1) * 64;
    const int kq = lane >> 4, ln15 = lane & 15;
    constexpr int K = CDIM, N = VDIM;
    const size_t bstride = (size_t)(K >> 6) * 1024;   // ushorts per n16 row

    auto stage = [&](int buf, int kt) {
        int k0 = kt << 6;
        #pragma unroll
        for (int r = 0; r < 4; r++) {
            int slot2 = tid + r * 256;
            int row = slot2 >> 3, g = slot2 & 7;
            int gk = ((g ^ (row & 7)) << 3);
            gload_lds16(A + (size_t)(mb + row) * K + k0 + gk,
                        &Al[buf * 8192 + slot2 * 8]);
        }
        #pragma unroll
        for (int r = 0; r < 4; r++) {
            int slot2 = tid + r * 256;          // 1024 slots x 16B = 16KB
            int n16 = slot2 >> 7, off = slot2 & 127;
            gload_lds16(Bf + (size_t)((nb >> 4) + n16) * bstride
                           + (size_t)kt * 1024 + off * 8,
                        &Bl[buf * 8192 + slot2 * 8]);
        }
    };

    f32x4 acc[4][4];
    #pragma unroll
    for (int i = 0; i < 4; i++)
        #pragma unroll
        for (int j = 0; j < 4; j++) acc[i][j] = (f32x4)0.f;

    stage(0, 0);
    stage(1, 1);
    for (int t = 0; t < 12; t++) {
        if (t < 11) wait_vm<8>();
        else        wait_vm<0>();
        barrier_asm();
        const ushort* Ab = &Al[(t & 1) * 8192];
        #pragma unroll
        for (int s = 0; s < 2; s++) {
            s16x8 af[4], bfr[4];
            #pragma unroll
            for (int i = 0; i < 4; i++) {
                int row = wm + i * 16 + ln15;
                int g = (s * 4 + kq) ^ (row & 7);
                af[i] = *(const s16x8*)&Ab[row * 64 + g * 8];
            }
            #pragma unroll
            for (int j = 0; j < 4; j++) {
                int n16 = (wn >> 4) + j;
                bfr[j] = *(const s16x8*)&Bl[(t & 1) * 8192 + n16 * 1024
                                            + (s * 512) + lane * 8];
            }
            #pragma unroll
            for (int i = 0; i < 4; i++)
                #pragma unroll
                for (int j = 0; j < 4; j++)
                    acc[i][j] = __builtin_amdgcn_mfma_f32_16x16x32_bf16(
                        af[i], bfr[j], acc[i][j], 0, 0, 0);
        }
        barrier_asm();
        if (t + 2 < 12) stage(t & 1, t + 2);
    }
    #pragma unroll
    for (int i = 0; i < 4; i++) {
        int rbase = mb + wm + i * 16 + (lane >> 4) * 4;
        #pragma unroll
        for (int j = 0; j < 4; j++) {
            int col = nb + wn + j * 16 + ln15;
            #pragma unroll
            for (int r = 0; r < 4; r++)
                C[(size_t)(rbase + r) * N + col] = acc[i][j][r];
        }
    }
}

// ---------------- WKV chunked scan ----------------
__global__ __launch_bounds__(256)
void k_wkv1(const float* __restrict__ kb, const float* __restrict__ vb,
            const float* __restrict__ decay, float* __restrict__ Stil) {
    int c = blockIdx.x / HNUM, h = blockIdx.x % HNUM;
    __shared__ float kl[4096], vl[4096], wsh[64];
    int tid = threadIdx.x;
    for (int idx = tid; idx < 4096; idx += 256) {
        int j = idx >> 6, cc = idx & 63;
        size_t g = (size_t)(c * LCH + j) * CDIM + h * 64 + cc;
        kl[idx] = kb[g]; vl[idx] = vb[g];
    }
    if (tid < 64) wsh[tid] = expf(-expf(decay[h * 64 + tid]));
    __syncthreads();
    int k = tid >> 2, v0 = (tid & 3) * 16;
    float w = wsh[k], f = 1.f;
    float s[16];
    #pragma unroll
    for (int i = 0; i < 16; i++) s[i] = 0.f;
    for (int j = 63; j >= 0; --j) {
        float kw = kl[j * 64 + k] * f;
        #pragma unroll
        for (int i = 0; i < 16; i++) s[i] += kw * vl[j * 64 + v0 + i];
        f *= w;
    }
    float* dst = Stil + ((size_t)(c * HNUM + h) << 12) + k * 64 + v0;
    #pragma unroll
    for (int i = 0; i < 16; i++) dst[i] = s[i];
}

// pass2+3 merged + fused GroupNorm*silu(gate) -> bf16 y
__global__ __launch_bounds__(256)
void k_wkv23(const float* __restrict__ rb, const float* __restrict__ kb,
             const float* __restrict__ vb, const float* __restrict__ Stil,
             const float* __restrict__ decay, const float* __restrict__ bonus,
             const float* __restrict__ gate, const float* __restrict__ gnw,
             ushort* __restrict__ y) {
    int c = blockIdx.x / HNUM, h = blockIdx.x % HNUM;
    __shared__ float rl[4096], kl[4096], vl[4096];
    __shared__ float part[4][4096];
    __shared__ float wsh[64], bsh[64];
    int tid = threadIdx.x;
    for (int idx = tid; idx < 4096; idx += 256) {
        int j = idx >> 6, cc = idx & 63;
        size_t g = (size_t)(c * LCH + j) * CDIM + h * 64 + cc;
        rl[idx] = rb[g]; kl[idx] = kb[g]; vl[idx] = vb[g];
    }
    if (tid < 64) {
        wsh[tid] = expf(-expf(decay[h * 64 + tid]));
        bsh[tid] = bonus[h * 64 + tid];
    }
    __syncthreads();
    int v = tid & 63, kg = tid >> 6;
    float S[16], wr[16], br[16], w64[16];
    #pragma unroll
    for (int i = 0; i < 16; i++) {
        S[i] = 0.f;
        wr[i] = wsh[kg * 16 + i];
        br[i] = bsh[kg * 16 + i];
        float t2 = wr[i];
        t2 *= t2; t2 *= t2; t2 *= t2; t2 *= t2; t2 *= t2; t2 *= t2;  // w^64
        w64[i] = t2;
    }
    for (int cc = 0; cc < c; cc++) {                 // chunk-prefix stitch
        const float* sp = Stil + ((size_t)(cc * HNUM + h) << 12);
        #pragma unroll
        for (int i = 0; i < 16; i++)
            S[i] = S[i] * w64[i] + sp[(kg * 16 + i) * 64 + v];
    }
    for (int j = 0; j < 64; j++) {
        float vj = vl[j * 64 + v];
        const float4* kp = (const float4*)&kl[j * 64 + kg * 16];
        const float4* rp = (const float4*)&rl[j * 64 + kg * 16];
        float rsum = 0.f;
        #pragma unroll
        for (int qq = 0; qq < 4; qq++) {
            float4 k4 = kp[qq], r4 = rp[qq];
            const float* kf = (const float*)&k4;
            const float* rf = (const float*)&r4;
            #pragma unroll
            for (int e = 0; e < 4; e++) {
                int i = qq * 4 + e;
                float a = kf[e] * vj;
                rsum += rf[e] * (S[i] + a * br[i]);
                S[i] = S[i] * wr[i] + a;
            }
        }
        part[kg][j * 64 + v] = rsum;
    }
    __syncthreads();
    for (int jj = 0; jj < 16; jj++) {
        int j = kg * 16 + jj;
        float o = part[0][j * 64 + v] + part[1][j * 64 + v] +
                  part[2][j * 64 + v] + part[3][j * 64 + v];
        float s = o, s2 = o * o;
        #pragma unroll
        for (int m = 32; m; m >>= 1) { s += __shfl_xor(s, m); s2 += __shfl_xor(s2, m); }
        float mu = s * (1.f / 64.f);
        float var = s2 * (1.f / 64.f) - mu * mu;
        float xg = (o - mu) * rsqrtf(var + 6.4e-4f);
        int t = c * LCH + j, col = h * 64 + v;
        float gv = gate[(size_t)t * CDIM + col];
        float silu = gv / (1.f + __expf(-gv));
        y[(size_t)t * CDIM + col] = f2bf((xg * gnw[col] + gnw[CDIM + col]) * silu);
    }
}

// ---------------- host ----------------
extern "C" void kernel_launch(void* const* d_in, const int* in_sizes, int n_in,
                              void* d_out, int out_size, void* d_ws, size_t ws_size,
                              hipStream_t stream) {
    const int*   tok      = (const int*)d_in[0];
    const float* embed    = (const float*)d_in[1];
    const float* embed_ln = (const float*)d_in[2];
    const float* tm_ln    = (const float*)d_in[3];
    const float* tm_ts    = (const float*)d_in[4];
    const float* tm_Wr    = (const float*)d_in[5];
    const float* tm_Wk    = (const float*)d_in[6];
    const float* tm_Wv    = (const float*)d_in[7];
    const float* tm_Wg    = (const float*)d_in[8];
    const float* tm_Wo    = (const float*)d_in[9];
    const float* tm_bonus = (const float*)d_in[10];
    const float* tm_decay = (const float*)d_in[11];
    const float* tm_gn    = (const float*)d_in[12];
    const float* cm_ln    = (const float*)d_in[13];
    const float* cm_ts    = (const float*)d_in[14];
    const float* cm_Win   = (const float*)d_in[15];
    const float* cm_Wout  = (const float*)d_in[16];
    const float* cm_Wg    = (const float*)d_in[17];
    const float* head_ln  = (const float*)d_in[18];
    const float* unembed  = (const float*)d_in[19];
    float* out = (float*)d_out;

    const size_t TC = (size_t)T_LEN * CDIM;
    char* wp = (char*)d_ws;
    auto alloc = [&](size_t bytes) {
        char* p = wp; wp += (bytes + 255) & ~(size_t)255; return p;
    };
    float*  x    = (float*)alloc(TC * 4);
    ushort* mix  = (ushort*)alloc(4 * TC * 2);
    float*  rkvg = (float*)alloc(4 * TC * 4);
    float*  gcm  = (float*)alloc(TC * 4);
    ushort* y    = (ushort*)alloc(TC * 2);
    ushort* hb   = (ushort*)alloc((size_t)T_LEN * FDIM * 2);
    float*  Stil = (float*)alloc((size_t)NCH * HNUM * 4096 * 4);
    ushort* ubuf = (ushort*)alloc((size_t)CDIM * VDIM * 2);
    size_t fixed_bytes = (size_t)(wp - (char*)d_ws);
    const size_t per_layer = ((size_t)WBUF_ELEMS * 2 + 255) & ~(size_t)255;
    bool all6 = (fixed_bytes + 6 * per_layer) <= ws_size;
    ushort* wbuf = (ushort*)alloc(all6 ? 6 * per_layer : per_layer);
    if ((size_t)(wp - (char*)d_ws) > ws_size) return;   // fail loudly, no UB

    if (all6) {
        k_conv_all<<<6 * 468 + 2358 + 1024, 256, 0, stream>>>(
            tm_Wr, tm_Wk, tm_Wv, tm_Wg, tm_Wo, cm_Wg, cm_Win, cm_Wout,
            unembed, wbuf, ubuf, tok, embed, embed_ln, x);
    } else {
        k_trans<<<dim3(VDIM / 64, CDIM / 64), 256, 0, stream>>>(
            unembed, ubuf, CDIM, VDIM);
        k_embed_ln<<<T_LEN, 256, 0, stream>>>(tok, embed, embed_ln, x);
    }

    dim3 g64(CDIM / 64, T_LEN / 64);        // (12,16)
    dim3 gQKVG(CDIM / 64, T_LEN / 64, 4);   // (12,16,4) 64x64 tiles
    dim3 gCmix(FDIM / 64 + CDIM / 64, T_LEN / 64);   // (54,16) 64x64 tiles

    for (int l = 0; l < LNUM; l++) {
        ushort* wl = all6 ? (ushort*)((char*)wbuf + (size_t)l * per_layer) : wbuf;
        if (!all6) {
            const size_t lo = (size_t)l * CDIM * CDIM;
            k_conv_layer<<<1872, 256, 0, stream>>>(
                tm_Wr + lo, tm_Wk + lo, tm_Wv + lo, tm_Wg + lo, tm_Wo + lo,
                cm_Wg + lo, cm_Win + (size_t)l * CDIM * FDIM,
                cm_Wout + (size_t)l * FDIM * CDIM, wl);
        }
        const float* dec = tm_decay + (size_t)l * HNUM * KDIM;
        const float* bon = tm_bonus + (size_t)l * HNUM * KDIM;

        // ---- time mixer ----
        k_lnlerp<4><<<T_LEN, 256, 0, stream>>>(x, tm_ln + (size_t)l * 2 * CDIM,
                                               tm_ts + (size_t)l * 4 * CDIM, mix);
        k_gemm_std<64,64,0,true><<<gQKVG, 256, 0, stream>>>(
            mix, wl, rkvg, nullptr, nullptr, nullptr, CDIM, CDIM);
        k_wkv1<<<NCH * HNUM, 256, 0, stream>>>(rkvg + TC, rkvg + 2 * TC, dec, Stil);
        k_wkv23<<<NCH * HNUM, 256, 0, stream>>>(rkvg, rkvg + TC, rkvg + 2 * TC,
            Stil, dec, bon, rkvg + 3 * TC, tm_gn + (size_t)l * 2 * CDIM, y);
        k_gemm_std<64,64,1,false><<<g64, 256, 0, stream>>>(
            y, wl + 4 * WSZ, x, nullptr, x, nullptr, CDIM, CDIM);

        // ---- channel mixer ----
        k_lnlerp<2><<<T_LEN, 256, 0, stream>>>(x, cm_ln + (size_t)l * 2 * CDIM,
                                               cm_ts + (size_t)l * 2 * CDIM, mix);
        k_cmix<<<gCmix, 256, 0, stream>>>(mix, wl, hb, gcm);
        k_gemm_std<64,64,3,false><<<g64, 256, 0, stream>>>(
            hb, wl + WOUT_OFF, x, nullptr, x, gcm, CDIM, FDIM);
    }

    k_ln_bf<<<T_LEN, 256, 0, stream>>>(x, head_ln, mix);
    k_gemm_head<<<3200, 256, 0, stream>>>(mix, ubuf, out);
}

// Round 14
// 876.349 us; speedup vs baseline: 1.1965x; 1.1965x over previous
//
#include <hip/hip_runtime.h>
#include <hip/hip_bf16.h>

#define T_LEN 1024
#define CDIM  768
#define HNUM  12
#define KDIM  64
#define LNUM  6
#define FDIM  2688
#define VDIM  50304
#define NCH   16     // wkv chunks
#define LCH   64     // chunk length

#define WSZ   (CDIM * CDIM)              // 589824
#define WIN_OFF  (6 * WSZ)               // 3538944
#define WOUT_OFF (WIN_OFF + CDIM * FDIM) // 5603328
#define WBUF_ELEMS (WOUT_OFF + FDIM * CDIM)  // 7667712 elems per layer

typedef __attribute__((ext_vector_type(4))) float f32x4;
typedef __attribute__((ext_vector_type(8))) short s16x8;

__device__ __forceinline__ ushort f2bf(float f) {
    union { float fv; unsigned u; } v; v.fv = f;
    unsigned r = v.u + 0x7fffu + ((v.u >> 16) & 1u);   // RNE
    return (ushort)(r >> 16);
}

__device__ __forceinline__ void gload_lds16(const ushort* g, ushort* l) {
    __builtin_amdgcn_global_load_lds(
        (const __attribute__((address_space(1))) void*)g,
        (__attribute__((address_space(3))) void*)l, 16, 0, 0);
}

template <int N_>
__device__ __forceinline__ void wait_vm() {
    if constexpr (N_ == 0)       asm volatile("s_waitcnt vmcnt(0)" ::: "memory");
    else if constexpr (N_ == 6)  asm volatile("s_waitcnt vmcnt(6)" ::: "memory");
    else if constexpr (N_ == 8)  asm volatile("s_waitcnt vmcnt(8)" ::: "memory");
    else if constexpr (N_ == 12) asm volatile("s_waitcnt vmcnt(12)" ::: "memory");
    else                         asm volatile("s_waitcnt vmcnt(16)" ::: "memory");
}
__device__ __forceinline__ void barrier_asm() {
    asm volatile("s_barrier" ::: "memory");
}

// ---- fragment-order store index for B^T[n][k] of a KxN weight (K=R rows) ---
// chunk (n16,k64,s)=1KB: lane l = kq*16+ln15 holds B^T[n16*16+ln15][k64*64+s*32+kq*8+e]
__device__ __forceinline__ size_t frag_idx(int nn, int k, int K) {
    int n16 = nn >> 4, ln15 = nn & 15;
    int k64 = k >> 6, s = (k >> 5) & 1, kq = (k >> 3) & 3;
    return ((size_t)(n16 * (K >> 6) + k64) * 2 + s) * 512 + (kq * 16 + ln15) * 8
           + (k & 4);
}

// -------- quad transpose+convert: 2 tk x 2 tn 64x64 tiles -> frag-order bf16
__device__ __forceinline__ void trans_quad(const float* __restrict__ in,
        ushort* __restrict__ out, int R, int C, int tkq, int tnp) {
    __shared__ float tl[2][2][64][65];
    int tid = threadIdx.x;
    int r = tid >> 4, c4 = (tid & 15) << 2;
    int k0 = tkq << 7, n0 = tnp << 7;
    float4 v[2][2][4];
    #pragma unroll
    for (int dk = 0; dk < 2; dk++)
        #pragma unroll
        for (int dn = 0; dn < 2; dn++)
            #pragma unroll
            for (int j = 0; j < 4; j++)
                v[dk][dn][j] = *(const float4*)
                    &in[(size_t)(k0 + dk * 64 + r + j * 16) * C + n0 + dn * 64 + c4];
    #pragma unroll
    for (int dk = 0; dk < 2; dk++)
        #pragma unroll
        for (int dn = 0; dn < 2; dn++)
            #pragma unroll
            for (int j = 0; j < 4; j++) {
                int rr = r + j * 16;
                tl[dk][dn][rr][c4 + 0] = v[dk][dn][j].x;
                tl[dk][dn][rr][c4 + 1] = v[dk][dn][j].y;
                tl[dk][dn][rr][c4 + 2] = v[dk][dn][j].z;
                tl[dk][dn][rr][c4 + 3] = v[dk][dn][j].w;
            }
    __syncthreads();
    #pragma unroll
    for (int dk = 0; dk < 2; dk++)
        #pragma unroll
        for (int dn = 0; dn < 2; dn++)
            #pragma unroll
            for (int j = 0; j < 4; j++) {
                int n = r + j * 16;
                ushort4 u;
                u.x = f2bf(tl[dk][dn][c4 + 0][n]);
                u.y = f2bf(tl[dk][dn][c4 + 1][n]);
                u.z = f2bf(tl[dk][dn][c4 + 2][n]);
                u.w = f2bf(tl[dk][dn][c4 + 3][n]);
                *(ushort4*)&out[frag_idx(n0 + dn * 64 + n, k0 + dk * 64 + c4, R)] = u;
            }
}

// single-tile variant (fallback path)
__device__ __forceinline__ void trans_tile(const float* __restrict__ in,
        ushort* __restrict__ out, int R, int C, int tk, int tn) {
    __shared__ float tile[64][65];
    int tid = threadIdx.x;
    int r = tid >> 4, c4 = (tid & 15) << 2;
    int k0 = tk << 6, n0 = tn << 6;
    #pragma unroll
    for (int j = 0; j < 4; j++) {
        int rr = r + j * 16;
        float4 f = *(const float4*)&in[(size_t)(k0 + rr) * C + n0 + c4];
        tile[rr][c4 + 0] = f.x; tile[rr][c4 + 1] = f.y;
        tile[rr][c4 + 2] = f.z; tile[rr][c4 + 3] = f.w;
    }
    __syncthreads();
    #pragma unroll
    for (int j = 0; j < 4; j++) {
        int n = r + j * 16;
        ushort4 u;
        u.x = f2bf(tile[c4 + 0][n]);
        u.y = f2bf(tile[c4 + 1][n]);
        u.z = f2bf(tile[c4 + 2][n]);
        u.w = f2bf(tile[c4 + 3][n]);
        *(ushort4*)&out[frag_idx(n0 + n, k0 + c4, R)] = u;
    }
}

__global__ __launch_bounds__(256)
void k_trans(const float* __restrict__ in, ushort* __restrict__ out, int R, int C) {
    trans_tile(in, out, R, C, blockIdx.y, blockIdx.x);
}

// ---------------- embed lookup + LN row (device func, also standalone) ------
__device__ __forceinline__ void embed_ln_row(int t, const int* __restrict__ tok,
        const float* __restrict__ embed, const float* __restrict__ wb,
        float* __restrict__ xout) {
    int tid = threadIdx.x;
    const float* row = embed + (size_t)tok[t] * CDIM;
    float v[3]; float s = 0.f, s2 = 0.f;
    #pragma unroll
    for (int j = 0; j < 3; j++) {
        v[j] = row[tid + j * 256]; s += v[j]; s2 += v[j] * v[j];
    }
    #pragma unroll
    for (int m = 32; m; m >>= 1) { s += __shfl_xor(s, m); s2 += __shfl_xor(s2, m); }
    __shared__ float rs[4], rq[4];
    int w = tid >> 6;
    if ((tid & 63) == 0) { rs[w] = s; rq[w] = s2; }
    __syncthreads();
    s = rs[0] + rs[1] + rs[2] + rs[3];
    s2 = rq[0] + rq[1] + rq[2] + rq[3];
    float mu = s * (1.f / CDIM);
    float inv = rsqrtf(s2 * (1.f / CDIM) - mu * mu + 1e-5f);
    #pragma unroll
    for (int j = 0; j < 3; j++) {
        int c = tid + j * 256;
        xout[(size_t)t * CDIM + c] = (v[j] - mu) * inv * wb[c] + wb[CDIM + c];
    }
}

__global__ __launch_bounds__(256)
void k_embed_ln(const int* __restrict__ tok, const float* __restrict__ embed,
                const float* __restrict__ wb, float* __restrict__ xout) {
    embed_ln_row(blockIdx.x, tok, embed, wb, xout);
}

// per-layer QUAD tile mapping: 468 quads per layer
__device__ __forceinline__ void conv_layer_quad(int t,
        const float* p0, const float* p1, const float* p2, const float* p3,
        const float* p4, const float* p5, const float* pWin, const float* pWout,
        ushort* wl) {
    const float* in; ushort* out; int R, C, tkq, tnp;
    if (t < 216) {                         // 6 square mats, 36 quads each
        int mi = t / 36, tt = t % 36;
        switch (mi) {
            case 0: in = p0; break; case 1: in = p1; break;
            case 2: in = p2; break; case 3: in = p3; break;
            case 4: in = p4; break; default: in = p5; break;
        }
        out = wl + (size_t)mi * WSZ; R = 768; C = 768;
        tkq = tt / 6; tnp = tt % 6;
    } else if (t < 342) {                  // Win: 6 tkq x 21 tnp
        int tt = t - 216;
        in = pWin; out = wl + WIN_OFF; R = 768; C = 2688;
        tkq = tt / 21; tnp = tt % 21;
    } else {                               // Wout: 21 tkq x 6 tnp
        int tt = t - 342;
        in = pWout; out = wl + WOUT_OFF; R = 2688; C = 768;
        tkq = tt / 6; tnp = tt % 6;
    }
    trans_quad(in, out, R, C, tkq, tnp);
}

// fallback per-layer converter (single tiles; only used if ws too small)
__global__ __launch_bounds__(256)
void k_conv_layer(const float* p0, const float* p1, const float* p2,
                  const float* p3, const float* p4, const float* p5,
                  const float* pWin, const float* pWout, ushort* wl) {
    int t = blockIdx.x;                    // 1872 single tiles
    const float* in; ushort* out; int R, C, tk, tn;
    if (t < 864) {
        int mi = t / 144, tt = t % 144;
        switch (mi) {
            case 0: in = p0; break; case 1: in = p1; break;
            case 2: in = p2; break; case 3: in = p3; break;
            case 4: in = p4; break; default: in = p5; break;
        }
        out = wl + (size_t)mi * WSZ; R = 768; C = 768;
        tk = tt / 12; tn = tt % 12;
    } else if (t < 1368) {
        int tt = t - 864;
        in = pWin; out = wl + WIN_OFF; R = 768; C = 2688;
        tk = tt / 42; tn = tt % 42;
    } else {
        int tt = t - 1368;
        in = pWout; out = wl + WOUT_OFF; R = 2688; C = 768;
        tk = tt / 12; tn = tt % 12;
    }
    trans_tile(in, out, R, C, tk, tn);
}

// all 6 layers + unembed + embed_ln in one launch
// grid = 6*468 + 2358 + 1024 = 6190
__global__ __launch_bounds__(256)
void k_conv_all(const float* Wr, const float* Wk, const float* Wv,
                const float* Wg, const float* Wo, const float* Wcg,
                const float* Win, const float* Wout, const float* unemb,
                ushort* wbuf, ushort* ubuf,
                const int* tok, const float* embed, const float* eln, float* x) {
    int b = blockIdx.x;
    if (b < 6 * 468) {
        int l = b / 468, t = b % 468;
        conv_layer_quad(t,
            Wr + (size_t)l * WSZ, Wk + (size_t)l * WSZ, Wv + (size_t)l * WSZ,
            Wg + (size_t)l * WSZ, Wo + (size_t)l * WSZ, Wcg + (size_t)l * WSZ,
            Win + (size_t)l * CDIM * FDIM, Wout + (size_t)l * FDIM * CDIM,
            wbuf + (size_t)l * WBUF_ELEMS);
    } else if (b < 6 * 468 + 2358) {
        int t = b - 6 * 468;               // unembed: 6 tkq x 393 tnp
        int tkq = t / 393, tnp = t % 393;
        trans_quad(unemb, ubuf, CDIM, VDIM, tkq, tnp);
    } else {
        embed_ln_row(b - (6 * 468 + 2358), tok, embed, eln, x);
    }
}

// ---------------- LayerNorm over C=768 -> bf16 (head input) ----------------
__global__ __launch_bounds__(256)
void k_ln_bf(const float* __restrict__ x, const float* __restrict__ wb,
             ushort* __restrict__ out) {
    int t = blockIdx.x, tid = threadIdx.x;
    float v[3]; float s = 0.f, s2 = 0.f;
    #pragma unroll
    for (int j = 0; j < 3; j++) {
        v[j] = x[(size_t)t * CDIM + tid + j * 256];
        s += v[j]; s2 += v[j] * v[j];
    }
    #pragma unroll
    for (int m = 32; m; m >>= 1) { s += __shfl_xor(s, m); s2 += __shfl_xor(s2, m); }
    __shared__ float rs[4], rq[4];
    int w = tid >> 6;
    if ((tid & 63) == 0) { rs[w] = s; rq[w] = s2; }
    __syncthreads();
    s = rs[0] + rs[1] + rs[2] + rs[3];
    s2 = rq[0] + rq[1] + rq[2] + rq[3];
    float mu = s * (1.f / CDIM);
    float inv = rsqrtf(s2 * (1.f / CDIM) - mu * mu + 1e-5f);
    #pragma unroll
    for (int j = 0; j < 3; j++) {
        int c = tid + j * 256;
        out[(size_t)t * CDIM + c] = f2bf((v[j] - mu) * inv * wb[c] + wb[CDIM + c]);
    }
}

// ---------------- fused LN + token-shift lerp -> NM bf16 mix buffers --------
template <int NM>
__global__ __launch_bounds__(256)
void k_lnlerp(const float* __restrict__ x, const float* __restrict__ lnw,
              const float* __restrict__ ts, ushort* __restrict__ mix) {
    int t = blockIdx.x, tid = threadIdx.x;
    bool has = (t > 0);
    float vb[3], va[3];
    float sb = 0.f, qb = 0.f, sa = 0.f, qa = 0.f;
    #pragma unroll
    for (int j = 0; j < 3; j++) {
        int c = tid + j * 256;
        vb[j] = x[(size_t)t * CDIM + c];
        sb += vb[j]; qb += vb[j] * vb[j];
        va[j] = has ? x[(size_t)(t - 1) * CDIM + c] : 0.f;
        sa += va[j]; qa += va[j] * va[j];
    }
    #pragma unroll
    for (int m = 32; m; m >>= 1) {
        sb += __shfl_xor(sb, m); qb += __shfl_xor(qb, m);
        sa += __shfl_xor(sa, m); qa += __shfl_xor(qa, m);
    }
    __shared__ float r0[4], r1[4], r2[4], r3[4];
    int w = tid >> 6;
    if ((tid & 63) == 0) { r0[w] = sb; r1[w] = qb; r2[w] = sa; r3[w] = qa; }
    __syncthreads();
    sb = r0[0] + r0[1] + r0[2] + r0[3]; qb = r1[0] + r1[1] + r1[2] + r1[3];
    sa = r2[0] + r2[1] + r2[2] + r2[3]; qa = r3[0] + r3[1] + r3[2] + r3[3];
    float mub = sb * (1.f / CDIM);
    float invb = rsqrtf(qb * (1.f / CDIM) - mub * mub + 1e-5f);
    float mua = sa * (1.f / CDIM);
    float inva = rsqrtf(qa * (1.f / CDIM) - mua * mua + 1e-5f);
    #pragma unroll
    for (int j = 0; j < 3; j++) {
        int c = tid + j * 256;
        float wgt = lnw[c], bia = lnw[CDIM + c];
        float xb = (vb[j] - mub) * invb * wgt + bia;
        float xa = has ? (va[j] - mua) * inva * wgt + bia : 0.f;
        #pragma unroll
        for (int m = 0; m < NM; m++) {
            float tv = ts[m * CDIM + c];
            mix[((size_t)m * T_LEN + t) * CDIM + c] = f2bf(xa + (xb - xa) * tv);
        }
    }
}

// ------- layer GEMM: A LDS-staged, B direct-from-global frag-order ----------
// EPI: 0 = f32, 1 = resid+f32, 2 = relu^2 -> bf16, 3 = resid + v*sigmoid(gate)
template <int BM, int BN, int EPI>
__device__ __forceinline__ void gemm_body(
        const ushort* __restrict__ A, const ushort* __restrict__ Bf,
        float* __restrict__ Cf, ushort* __restrict__ Cb,
        const float* __restrict__ resid, const float* __restrict__ gate,
        int N, int K, int mb, int nb, ushort* Al) {
    const int tid = threadIdx.x, lane = tid & 63, wave = tid >> 6;
    constexpr int WM = BM / 2, WN = BN / 2, FM = WM / 16, FN = WN / 16;
    const int wm = (wave >> 1) * WM, wn = (wave & 1) * WN;
    constexpr int AR = BM / 32;          // 16B A-slots per thread per k-tile
    constexpr int LD = AR + 2 * FN;      // vmem ops per k-tile per thread
    const int kq = lane >> 4, ln15 = lane & 15;

    const size_t bstride = (size_t)(K >> 6) * 2048;   // bytes per n16 tile-row
    const char* bbase = (const char*)Bf +
        (size_t)((nb + wn) >> 4) * bstride + lane * 16;

    auto stageA = [&](int buf, int kt) {
        int k0 = kt << 6;
        #pragma unroll
        for (int r = 0; r < AR; r++) {
            int slot = tid + r * 256;
            int row = slot >> 3, g = slot & 7;
            int gk = ((g ^ (row & 7)) << 3);
            gload_lds16(A + (size_t)(mb + row) * K + k0 + gk,
                        &Al[buf * BM * 64 + slot * 8]);
        }
    };
    auto loadB = [&](s16x8 (&dst)[2][FN], int kt) {
        const char* p = bbase + (size_t)kt * 2048;
        #pragma unroll
        for (int s = 0; s < 2; s++)
            #pragma unroll
            for (int j = 0; j < FN; j++)
                dst[s][j] = *(const s16x8*)(p + (size_t)j * bstride + s * 1024);
    };

    f32x4 acc[FM][FN];
    #pragma unroll
    for (int i = 0; i < FM; i++)
        #pragma unroll
        for (int j = 0; j < FN; j++) acc[i][j] = (f32x4)0.f;

    auto compute = [&](const ushort* Ab, s16x8 (&bfr)[2][FN]) {
        #pragma unroll
        for (int s = 0; s < 2; s++) {
            s16x8 af[FM];
            #pragma unroll
            for (int i = 0; i < FM; i++) {
                int row = wm + i * 16 + ln15;
                int g = (s * 4 + kq) ^ (row & 7);
                af[i] = *(const s16x8*)&Ab[row * 64 + g * 8];
            }
            #pragma unroll
            for (int i = 0; i < FM; i++)
                #pragma unroll
                for (int j = 0; j < FN; j++)
                    acc[i][j] = __builtin_amdgcn_mfma_f32_16x16x32_bf16(
                        af[i], bfr[s][j], acc[i][j], 0, 0, 0);
        }
    };

    const int nt = K >> 6;               // even (12 or 42) at every call site
    s16x8 b0[2][FN], b1[2][FN];
    stageA(0, 0); loadB(b0, 0);
    stageA(1, 1); loadB(b1, 1);
    for (int t = 0; t < nt; t += 2) {
        wait_vm<LD>();                   // tile t done; tile t+1 in flight
        barrier_asm();
        compute(Al, b0);
        barrier_asm();
        if (t + 2 < nt) { stageA(0, t + 2); loadB(b0, t + 2); }
        if (t + 2 < nt) wait_vm<LD>();   // tile t+1 done; tile t+2 in flight
        else            wait_vm<0>();
        barrier_asm();
        compute(Al + BM * 64, b1);
        barrier_asm();
        if (t + 3 < nt) { stageA(1, t + 3); loadB(b1, t + 3); }
    }
    #pragma unroll
    for (int i = 0; i < FM; i++) {
        int rbase = mb + wm + i * 16 + (lane >> 4) * 4;
        #pragma unroll
        for (int j = 0; j < FN; j++) {
            int col = nb + wn + j * 16 + (lane & 15);
            #pragma unroll
            for (int r = 0; r < 4; r++) {
                size_t idx = (size_t)(rbase + r) * N + col;
                float vv = acc[i][j][r];
                if constexpr (EPI == 0) {
                    Cf[idx] = vv;
                } else if constexpr (EPI == 1) {
                    Cf[idx] = resid[idx] + vv;
                } else if constexpr (EPI == 2) {
                    float z = vv > 0.f ? vv * vv : 0.f;
                    Cb[idx] = f2bf(z);
                } else {
                    float gv = gate[idx];
                    Cf[idx] = resid[idx] + vv / (1.f + __expf(-gv));
                }
            }
        }
    }
}

template <int BM, int BN, int EPI, bool BATCH>
__global__ __launch_bounds__(256)
void k_gemm_std(const ushort* __restrict__ A, const ushort* __restrict__ Bf,
                float* __restrict__ Cf, ushort* __restrict__ Cb,
                const float* __restrict__ resid, const float* __restrict__ gate,
                int N, int K) {
    __shared__ __align__(16) ushort Al[2 * BM * 64];
    if constexpr (BATCH) {
        int z = blockIdx.z;
        A  += (size_t)z * T_LEN * CDIM;
        Bf += (size_t)z * CDIM * CDIM;
        Cf += (size_t)z * T_LEN * CDIM;
    }
    gemm_body<BM, BN, EPI>(A, Bf, Cf, Cb, resid, gate, N, K,
                           blockIdx.y * BM, blockIdx.x * BN, Al);
}

// ------- head GEMM: BOTH operands LDS-staged (proven fastest for head) ------
__global__ __launch_bounds__(256)
void k_gemm_head(const ushort* __restrict__ A, const ushort* __restrict__ Bf,
                 float* __restrict__ C) {
    __shared__ __align__(16) ushort Al[2 * 128 * 64];
    __shared__ __align__(16) ushort Bl[2 * 128 * 64];
    int id = blockIdx.x;
    int xcd = id & 7, slot = id >> 3;
    int mbi = slot & 7, nbl = slot >> 3;
    int nbi = nbl * 8 + xcd;                 // bijective, balanced
    if (nbi >= VDIM / 128) return;
    const int mb = mbi * 128, nb = nbi * 128;
    const int tid = threadIdx.x, lane = tid & 63, wave = tid >> 6;
    const int wm = (wave >> 1) * 64, wn = (wave & 1) * 64;
    const int kq = lane >> 4, ln15 = lane & 15;
    constexpr int K = CDIM, N = VDIM;
    const size_t bstride = (size_t)(K >> 6) * 1024;   // ushorts per n16 row

    auto stage = [&](int buf, int kt) {
        int k0 = kt << 6;
        #pragma unroll
        for (int r = 0; r < 4; r++) {
            int slot2 = tid + r * 256;
            int row = slot2 >> 3, g = slot2 & 7;
            int gk = ((g ^ (row & 7)) << 3);
            gload_lds16(A + (size_t)(mb + row) * K + k0 + gk,
                        &Al[buf * 8192 + slot2 * 8]);
        }
        #pragma unroll
        for (int r = 0; r < 4; r++) {
            int slot2 = tid + r * 256;          // 1024 slots x 16B = 16KB
            int n16 = slot2 >> 7, off = slot2 & 127;
            gload_lds16(Bf + (size_t)((nb >> 4) + n16) * bstride
                           + (size_t)kt * 1024 + off * 8,
                        &Bl[buf * 8192 + slot2 * 8]);
        }
    };

    f32x4 acc[4][4];
    #pragma unroll
    for (int i = 0; i < 4; i++)
        #pragma unroll
        for (int j = 0; j < 4; j++) acc[i][j] = (f32x4)0.f;

    stage(0, 0);
    stage(1, 1);
    for (int t = 0; t < 12; t++) {
        if (t < 11) wait_vm<8>();
        else        wait_vm<0>();
        barrier_asm();
        const ushort* Ab = &Al[(t & 1) * 8192];
        #pragma unroll
        for (int s = 0; s < 2; s++) {
            s16x8 af[4], bfr[4];
            #pragma unroll
            for (int i = 0; i < 4; i++) {
                int row = wm + i * 16 + ln15;
                int g = (s * 4 + kq) ^ (row & 7);
                af[i] = *(const s16x8*)&Ab[row * 64 + g * 8];
            }
            #pragma unroll
            for (int j = 0; j < 4; j++) {
                int n16 = (wn >> 4) + j;
                bfr[j] = *(const s16x8*)&Bl[(t & 1) * 8192 + n16 * 1024
                                            + (s * 512) + lane * 8];
            }
            #pragma unroll
            for (int i = 0; i < 4; i++)
                #pragma unroll
                for (int j = 0; j < 4; j++)
                    acc[i][j] = __builtin_amdgcn_mfma_f32_16x16x32_bf16(
                        af[i], bfr[j], acc[i][j], 0, 0, 0);
        }
        barrier_asm();
        if (t + 2 < 12) stage(t & 1, t + 2);
    }
    #pragma unroll
    for (int i = 0; i < 4; i++) {
        int rbase = mb + wm + i * 16 + (lane >> 4) * 4;
        #pragma unroll
        for (int j = 0; j < 4; j++) {
            int col = nb + wn + j * 16 + ln15;
            #pragma unroll
            for (int r = 0; r < 4; r++)
                C[(size_t)(rbase + r) * N + col] = acc[i][j][r];
        }
    }
}

// channel-mixer Win (relu^2 -> hb) + Wcg (f32 gcm) merged, 128x64 tiles
__global__ __launch_bounds__(256)
void k_cmix(const ushort* __restrict__ mix, const ushort* __restrict__ wl,
            ushort* __restrict__ hb, float* __restrict__ gcm) {
    __shared__ __align__(16) ushort Al[2 * 128 * 64];
    int bx = blockIdx.x, mb = blockIdx.y * 128;
    if (bx < FDIM / 64) {
        gemm_body<128, 64, 2>(mix, wl + WIN_OFF, nullptr, hb, nullptr, nullptr,
                              FDIM, CDIM, mb, bx * 64, Al);
    } else {
        gemm_body<128, 64, 0>(mix + (size_t)T_LEN * CDIM, wl + 5 * WSZ, gcm,
                              nullptr, nullptr, nullptr, CDIM, CDIM, mb,
                              (bx - FDIM / 64) * 64, Al);
    }
}

// ---------------- WKV chunked scan ----------------
__global__ __launch_bounds__(256)
void k_wkv1(const float* __restrict__ kb, const float* __restrict__ vb,
            const float* __restrict__ decay, float* __restrict__ Stil) {
    int c = blockIdx.x / HNUM, h = blockIdx.x % HNUM;
    __shared__ float kl[4096], vl[4096], wsh[64];
    int tid = threadIdx.x;
    for (int idx = tid; idx < 4096; idx += 256) {
        int j = idx >> 6, cc = idx & 63;
        size_t g = (size_t)(c * LCH + j) * CDIM + h * 64 + cc;
        kl[idx] = kb[g]; vl[idx] = vb[g];
    }
    if (tid < 64) wsh[tid] = expf(-expf(decay[h * 64 + tid]));
    __syncthreads();
    int k = tid >> 2, v0 = (tid & 3) * 16;
    float w = wsh[k], f = 1.f;
    float s[16];
    #pragma unroll
    for (int i = 0; i < 16; i++) s[i] = 0.f;
    for (int j = 63; j >= 0; --j) {
        float kw = kl[j * 64 + k] * f;
        #pragma unroll
        for (int i = 0; i < 16; i++) s[i] += kw * vl[j * 64 + v0 + i];
        f *= w;
    }
    float* dst = Stil + ((size_t)(c * HNUM + h) << 12) + k * 64 + v0;
    #pragma unroll
    for (int i = 0; i < 16; i++) dst[i] = s[i];
}

// pass2+3 merged + fused GroupNorm*silu(gate) -> bf16 y
__global__ __launch_bounds__(256)
void k_wkv23(const float* __restrict__ rb, const float* __restrict__ kb,
             const float* __restrict__ vb, const float* __restrict__ Stil,
             const float* __restrict__ decay, const float* __restrict__ bonus,
             const float* __restrict__ gate, const float* __restrict__ gnw,
             ushort* __restrict__ y) {
    int c = blockIdx.x / HNUM, h = blockIdx.x % HNUM;
    __shared__ float rl[4096], kl[4096], vl[4096];
    __shared__ float part[4][4096];
    __shared__ float wsh[64], bsh[64];
    int tid = threadIdx.x;
    for (int idx = tid; idx < 4096; idx += 256) {
        int j = idx >> 6, cc = idx & 63;
        size_t g = (size_t)(c * LCH + j) * CDIM + h * 64 + cc;
        rl[idx] = rb[g]; kl[idx] = kb[g]; vl[idx] = vb[g];
    }
    if (tid < 64) {
        wsh[tid] = expf(-expf(decay[h * 64 + tid]));
        bsh[tid] = bonus[h * 64 + tid];
    }
    __syncthreads();
    int v = tid & 63, kg = tid >> 6;
    float S[16], wr[16], br[16], w64[16];
    #pragma unroll
    for (int i = 0; i < 16; i++) {
        S[i] = 0.f;
        wr[i] = wsh[kg * 16 + i];
        br[i] = bsh[kg * 16 + i];
        float t2 = wr[i];
        t2 *= t2; t2 *= t2; t2 *= t2; t2 *= t2; t2 *= t2; t2 *= t2;  // w^64
        w64[i] = t2;
    }
    for (int cc = 0; cc < c; cc++) {                 // chunk-prefix stitch
        const float* sp = Stil + ((size_t)(cc * HNUM + h) << 12);
        #pragma unroll
        for (int i = 0; i < 16; i++)
            S[i] = S[i] * w64[i] + sp[(kg * 16 + i) * 64 + v];
    }
    for (int j = 0; j < 64; j++) {
        float vj = vl[j * 64 + v];
        const float4* kp = (const float4*)&kl[j * 64 + kg * 16];
        const float4* rp = (const float4*)&rl[j * 64 + kg * 16];
        float rsum = 0.f;
        #pragma unroll
        for (int qq = 0; qq < 4; qq++) {
            float4 k4 = kp[qq], r4 = rp[qq];
            const float* kf = (const float*)&k4;
            const float* rf = (const float*)&r4;
            #pragma unroll
            for (int e = 0; e < 4; e++) {
                int i = qq * 4 + e;
                float a = kf[e] * vj;
                rsum += rf[e] * (S[i] + a * br[i]);
                S[i] = S[i] * wr[i] + a;
            }
        }
        part[kg][j * 64 + v] = rsum;
    }
    __syncthreads();
    for (int jj = 0; jj < 16; jj++) {
        int j = kg * 16 + jj;
        float o = part[0][j * 64 + v] + part[1][j * 64 + v] +
                  part[2][j * 64 + v] + part[3][j * 64 + v];
        float s = o, s2 = o * o;
        #pragma unroll
        for (int m = 32; m; m >>= 1) { s += __shfl_xor(s, m); s2 += __shfl_xor(s2, m); }
        float mu = s * (1.f / 64.f);
        float var = s2 * (1.f / 64.f) - mu * mu;
        float xg = (o - mu) * rsqrtf(var + 6.4e-4f);
        int t = c * LCH + j, col = h * 64 + v;
        float gv = gate[(size_t)t * CDIM + col];
        float silu = gv / (1.f + __expf(-gv));
        y[(size_t)t * CDIM + col] = f2bf((xg * gnw[col] + gnw[CDIM + col]) * silu);
    }
}

// ---------------- host ----------------
extern "C" void kernel_launch(void* const* d_in, const int* in_sizes, int n_in,
                              void* d_out, int out_size, void* d_ws, size_t ws_size,
                              hipStream_t stream) {
    const int*   tok      = (const int*)d_in[0];
    const float* embed    = (const float*)d_in[1];
    const float* embed_ln = (const float*)d_in[2];
    const float* tm_ln    = (const float*)d_in[3];
    const float* tm_ts    = (const float*)d_in[4];
    const float* tm_Wr    = (const float*)d_in[5];
    const float* tm_Wk    = (const float*)d_in[6];
    const float* tm_Wv    = (const float*)d_in[7];
    const float* tm_Wg    = (const float*)d_in[8];
    const float* tm_Wo    = (const float*)d_in[9];
    const float* tm_bonus = (const float*)d_in[10];
    const float* tm_decay = (const float*)d_in[11];
    const float* tm_gn    = (const float*)d_in[12];
    const float* cm_ln    = (const float*)d_in[13];
    const float* cm_ts    = (const float*)d_in[14];
    const float* cm_Win   = (const float*)d_in[15];
    const float* cm_Wout  = (const float*)d_in[16];
    const float* cm_Wg    = (const float*)d_in[17];
    const float* head_ln  = (const float*)d_in[18];
    const float* unembed  = (const float*)d_in[19];
    float* out = (float*)d_out;

    const size_t TC = (size_t)T_LEN * CDIM;
    char* wp = (char*)d_ws;
    auto alloc = [&](size_t bytes) {
        char* p = wp; wp += (bytes + 255) & ~(size_t)255; return p;
    };
    float*  x    = (float*)alloc(TC * 4);
    ushort* mix  = (ushort*)alloc(4 * TC * 2);
    float*  rkvg = (float*)alloc(4 * TC * 4);
    float*  gcm  = (float*)alloc(TC * 4);
    ushort* y    = (ushort*)alloc(TC * 2);
    ushort* hb   = (ushort*)alloc((size_t)T_LEN * FDIM * 2);
    float*  Stil = (float*)alloc((size_t)NCH * HNUM * 4096 * 4);
    ushort* ubuf = (ushort*)alloc((size_t)CDIM * VDIM * 2);
    size_t fixed_bytes = (size_t)(wp - (char*)d_ws);
    const size_t per_layer = ((size_t)WBUF_ELEMS * 2 + 255) & ~(size_t)255;
    bool all6 = (fixed_bytes + 6 * per_layer) <= ws_size;
    ushort* wbuf = (ushort*)alloc(all6 ? 6 * per_layer : per_layer);
    if ((size_t)(wp - (char*)d_ws) > ws_size) return;   // fail loudly, no UB

    if (all6) {
        k_conv_all<<<6 * 468 + 2358 + 1024, 256, 0, stream>>>(
            tm_Wr, tm_Wk, tm_Wv, tm_Wg, tm_Wo, cm_Wg, cm_Win, cm_Wout,
            unembed, wbuf, ubuf, tok, embed, embed_ln, x);
    } else {
        k_trans<<<dim3(VDIM / 64, CDIM / 64), 256, 0, stream>>>(
            unembed, ubuf, CDIM, VDIM);
        k_embed_ln<<<T_LEN, 256, 0, stream>>>(tok, embed, embed_ln, x);
    }

    dim3 g64(CDIM / 64, T_LEN / 64);        // (12,16)
    dim3 gQKVG(CDIM / 64, T_LEN / 128, 4);  // (12,8,4) 128x64 tiles
    dim3 gCmix(FDIM / 64 + CDIM / 64, T_LEN / 128);  // (54,8) 128x64 tiles

    for (int l = 0; l < LNUM; l++) {
        ushort* wl = all6 ? (ushort*)((char*)wbuf + (size_t)l * per_layer) : wbuf;
        if (!all6) {
            const size_t lo = (size_t)l * CDIM * CDIM;
            k_conv_layer<<<1872, 256, 0, stream>>>(
                tm_Wr + lo, tm_Wk + lo, tm_Wv + lo, tm_Wg + lo, tm_Wo + lo,
                cm_Wg + lo, cm_Win + (size_t)l * CDIM * FDIM,
                cm_Wout + (size_t)l * FDIM * CDIM, wl);
        }
        const float* dec = tm_decay + (size_t)l * HNUM * KDIM;
        const float* bon = tm_bonus + (size_t)l * HNUM * KDIM;

        // ---- time mixer ----
        k_lnlerp<4><<<T_LEN, 256, 0, stream>>>(x, tm_ln + (size_t)l * 2 * CDIM,
                                               tm_ts + (size_t)l * 4 * CDIM, mix);
        k_gemm_std<128,64,0,true><<<gQKVG, 256, 0, stream>>>(
            mix, wl, rkvg, nullptr, nullptr, nullptr, CDIM, CDIM);
        k_wkv1<<<NCH * HNUM, 256, 0, stream>>>(rkvg + TC, rkvg + 2 * TC, dec, Stil);
        k_wkv23<<<NCH * HNUM, 256, 0, stream>>>(rkvg, rkvg + TC, rkvg + 2 * TC,
            Stil, dec, bon, rkvg + 3 * TC, tm_gn + (size_t)l * 2 * CDIM, y);
        k_gemm_std<64,64,1,false><<<g64, 256, 0, stream>>>(
            y, wl + 4 * WSZ, x, nullptr, x, nullptr, CDIM, CDIM);

        // ---- channel mixer ----
        k_lnlerp<2><<<T_LEN, 256, 0, stream>>>(x, cm_ln + (size_t)l * 2 * CDIM,
                                               cm_ts + (size_t)l * 2 * CDIM, mix);
        k_cmix<<<gCmix, 256, 0, stream>>>(mix, wl, hb, gcm);
        k_gemm_std<64,64,3,false><<<g64, 256, 0, stream>>>(
            hb, wl + WOUT_OFF, x, nullptr, x, gcm, CDIM, FDIM);
    }

    k_ln_bf<<<T_LEN, 256, 0, stream>>>(x, head_ln, mix);
    k_gemm_head<<<3200, 256, 0, stream>>>(mix, ubuf, out);
}

// Round 15
// 859.807 us; speedup vs baseline: 1.2196x; 1.0192x over previous
//
#include <hip/hip_runtime.h>
#include <hip/hip_bf16.h>

#define T_LEN 1024
#define CDIM  768
#define HNUM  12
#define KDIM  64
#define LNUM  6
#define FDIM  2688
#define VDIM  50304
#define NCH   16     // wkv chunks
#define LCH   64     // chunk length

#define WSZ   (CDIM * CDIM)              // 589824
#define WIN_OFF  (6 * WSZ)               // 3538944
#define WOUT_OFF (WIN_OFF + CDIM * FDIM) // 5603328
#define WBUF_ELEMS (WOUT_OFF + FDIM * CDIM)  // 7667712 elems per layer

typedef __attribute__((ext_vector_type(4))) float f32x4;
typedef __attribute__((ext_vector_type(8))) short s16x8;

__device__ __forceinline__ ushort f2bf(float f) {
    union { float fv; unsigned u; } v; v.fv = f;
    unsigned r = v.u + 0x7fffu + ((v.u >> 16) & 1u);   // RNE
    return (ushort)(r >> 16);
}
__device__ __forceinline__ float bf2f(ushort u) {
    union { unsigned u32; float f; } v; v.u32 = (unsigned)u << 16; return v.f;
}

__device__ __forceinline__ void gload_lds16(const ushort* g, ushort* l) {
    __builtin_amdgcn_global_load_lds(
        (const __attribute__((address_space(1))) void*)g,
        (__attribute__((address_space(3))) void*)l, 16, 0, 0);
}

template <int N_>
__device__ __forceinline__ void wait_vm() {
    if constexpr (N_ == 0)       asm volatile("s_waitcnt vmcnt(0)" ::: "memory");
    else if constexpr (N_ == 6)  asm volatile("s_waitcnt vmcnt(6)" ::: "memory");
    else if constexpr (N_ == 8)  asm volatile("s_waitcnt vmcnt(8)" ::: "memory");
    else if constexpr (N_ == 12) asm volatile("s_waitcnt vmcnt(12)" ::: "memory");
    else                         asm volatile("s_waitcnt vmcnt(16)" ::: "memory");
}
__device__ __forceinline__ void barrier_asm() {
    asm volatile("s_barrier" ::: "memory");
}

// ---- fragment-order store index for B^T[n][k] of a KxN weight (K=R rows) ---
__device__ __forceinline__ size_t frag_idx(int nn, int k, int K) {
    int n16 = nn >> 4, ln15 = nn & 15;
    int k64 = k >> 6, s = (k >> 5) & 1, kq = (k >> 3) & 3;
    return ((size_t)(n16 * (K >> 6) + k64) * 2 + s) * 512 + (kq * 16 + ln15) * 8
           + (k & 4);
}

// -------- quad transpose+convert: 2 tk x 2 tn 64x64 tiles -> frag-order bf16
__device__ __forceinline__ void trans_quad(const float* __restrict__ in,
        ushort* __restrict__ out, int R, int C, int tkq, int tnp) {
    __shared__ float tl[2][2][64][65];
    int tid = threadIdx.x;
    int r = tid >> 4, c4 = (tid & 15) << 2;
    int k0 = tkq << 7, n0 = tnp << 7;
    float4 v[2][2][4];
    #pragma unroll
    for (int dk = 0; dk < 2; dk++)
        #pragma unroll
        for (int dn = 0; dn < 2; dn++)
            #pragma unroll
            for (int j = 0; j < 4; j++)
                v[dk][dn][j] = *(const float4*)
                    &in[(size_t)(k0 + dk * 64 + r + j * 16) * C + n0 + dn * 64 + c4];
    #pragma unroll
    for (int dk = 0; dk < 2; dk++)
        #pragma unroll
        for (int dn = 0; dn < 2; dn++)
            #pragma unroll
            for (int j = 0; j < 4; j++) {
                int rr = r + j * 16;
                tl[dk][dn][rr][c4 + 0] = v[dk][dn][j].x;
                tl[dk][dn][rr][c4 + 1] = v[dk][dn][j].y;
                tl[dk][dn][rr][c4 + 2] = v[dk][dn][j].z;
                tl[dk][dn][rr][c4 + 3] = v[dk][dn][j].w;
            }
    __syncthreads();
    #pragma unroll
    for (int dk = 0; dk < 2; dk++)
        #pragma unroll
        for (int dn = 0; dn < 2; dn++)
            #pragma unroll
            for (int j = 0; j < 4; j++) {
                int n = r + j * 16;
                ushort4 u;
                u.x = f2bf(tl[dk][dn][c4 + 0][n]);
                u.y = f2bf(tl[dk][dn][c4 + 1][n]);
                u.z = f2bf(tl[dk][dn][c4 + 2][n]);
                u.w = f2bf(tl[dk][dn][c4 + 3][n]);
                *(ushort4*)&out[frag_idx(n0 + dn * 64 + n, k0 + dk * 64 + c4, R)] = u;
            }
}

// single-tile variant (fallback path)
__device__ __forceinline__ void trans_tile(const float* __restrict__ in,
        ushort* __restrict__ out, int R, int C, int tk, int tn) {
    __shared__ float tile[64][65];
    int tid = threadIdx.x;
    int r = tid >> 4, c4 = (tid & 15) << 2;
    int k0 = tk << 6, n0 = tn << 6;
    #pragma unroll
    for (int j = 0; j < 4; j++) {
        int rr = r + j * 16;
        float4 f = *(const float4*)&in[(size_t)(k0 + rr) * C + n0 + c4];
        tile[rr][c4 + 0] = f.x; tile[rr][c4 + 1] = f.y;
        tile[rr][c4 + 2] = f.z; tile[rr][c4 + 3] = f.w;
    }
    __syncthreads();
    #pragma unroll
    for (int j = 0; j < 4; j++) {
        int n = r + j * 16;
        ushort4 u;
        u.x = f2bf(tile[c4 + 0][n]);
        u.y = f2bf(tile[c4 + 1][n]);
        u.z = f2bf(tile[c4 + 2][n]);
        u.w = f2bf(tile[c4 + 3][n]);
        *(ushort4*)&out[frag_idx(n0 + n, k0 + c4, R)] = u;
    }
}

__global__ __launch_bounds__(256)
void k_trans(const float* __restrict__ in, ushort* __restrict__ out, int R, int C) {
    trans_tile(in, out, R, C, blockIdx.y, blockIdx.x);
}

// ---------------- embed lookup + LN row (device func, also standalone) ------
__device__ __forceinline__ void embed_ln_row(int t, const int* __restrict__ tok,
        const float* __restrict__ embed, const float* __restrict__ wb,
        float* __restrict__ xout) {
    int tid = threadIdx.x;
    const float* row = embed + (size_t)tok[t] * CDIM;
    float v[3]; float s = 0.f, s2 = 0.f;
    #pragma unroll
    for (int j = 0; j < 3; j++) {
        v[j] = row[tid + j * 256]; s += v[j]; s2 += v[j] * v[j];
    }
    #pragma unroll
    for (int m = 32; m; m >>= 1) { s += __shfl_xor(s, m); s2 += __shfl_xor(s2, m); }
    __shared__ float rs[4], rq[4];
    int w = tid >> 6;
    if ((tid & 63) == 0) { rs[w] = s; rq[w] = s2; }
    __syncthreads();
    s = rs[0] + rs[1] + rs[2] + rs[3];
    s2 = rq[0] + rq[1] + rq[2] + rq[3];
    float mu = s * (1.f / CDIM);
    float inv = rsqrtf(s2 * (1.f / CDIM) - mu * mu + 1e-5f);
    #pragma unroll
    for (int j = 0; j < 3; j++) {
        int c = tid + j * 256;
        xout[(size_t)t * CDIM + c] = (v[j] - mu) * inv * wb[c] + wb[CDIM + c];
    }
}

__global__ __launch_bounds__(256)
void k_embed_ln(const int* __restrict__ tok, const float* __restrict__ embed,
                const float* __restrict__ wb, float* __restrict__ xout) {
    embed_ln_row(blockIdx.x, tok, embed, wb, xout);
}

// per-layer QUAD tile mapping: 468 quads per layer
__device__ __forceinline__ void conv_layer_quad(int t,
        const float* p0, const float* p1, const float* p2, const float* p3,
        const float* p4, const float* p5, const float* pWin, const float* pWout,
        ushort* wl) {
    const float* in; ushort* out; int R, C, tkq, tnp;
    if (t < 216) {                         // 6 square mats, 36 quads each
        int mi = t / 36, tt = t % 36;
        switch (mi) {
            case 0: in = p0; break; case 1: in = p1; break;
            case 2: in = p2; break; case 3: in = p3; break;
            case 4: in = p4; break; default: in = p5; break;
        }
        out = wl + (size_t)mi * WSZ; R = 768; C = 768;
        tkq = tt / 6; tnp = tt % 6;
    } else if (t < 342) {                  // Win: 6 tkq x 21 tnp
        int tt = t - 216;
        in = pWin; out = wl + WIN_OFF; R = 768; C = 2688;
        tkq = tt / 21; tnp = tt % 21;
    } else {                               // Wout: 21 tkq x 6 tnp
        int tt = t - 342;
        in = pWout; out = wl + WOUT_OFF; R = 2688; C = 768;
        tkq = tt / 6; tnp = tt % 6;
    }
    trans_quad(in, out, R, C, tkq, tnp);
}

// fallback per-layer converter (single tiles; only used if ws too small)
__global__ __launch_bounds__(256)
void k_conv_layer(const float* p0, const float* p1, const float* p2,
                  const float* p3, const float* p4, const float* p5,
                  const float* pWin, const float* pWout, ushort* wl) {
    int t = blockIdx.x;                    // 1872 single tiles
    const float* in; ushort* out; int R, C, tk, tn;
    if (t < 864) {
        int mi = t / 144, tt = t % 144;
        switch (mi) {
            case 0: in = p0; break; case 1: in = p1; break;
            case 2: in = p2; break; case 3: in = p3; break;
            case 4: in = p4; break; default: in = p5; break;
        }
        out = wl + (size_t)mi * WSZ; R = 768; C = 768;
        tk = tt / 12; tn = tt % 12;
    } else if (t < 1368) {
        int tt = t - 864;
        in = pWin; out = wl + WIN_OFF; R = 768; C = 2688;
        tk = tt / 42; tn = tt % 42;
    } else {
        int tt = t - 1368;
        in = pWout; out = wl + WOUT_OFF; R = 2688; C = 768;
        tk = tt / 12; tn = tt % 12;
    }
    trans_tile(in, out, R, C, tk, tn);
}

// all 6 layers + unembed + embed_ln in one launch
// grid = 6*468 + 2358 + 1024 = 6190
__global__ __launch_bounds__(256)
void k_conv_all(const float* Wr, const float* Wk, const float* Wv,
                const float* Wg, const float* Wo, const float* Wcg,
                const float* Win, const float* Wout, const float* unemb,
                ushort* wbuf, ushort* ubuf,
                const int* tok, const float* embed, const float* eln, float* x) {
    int b = blockIdx.x;
    if (b < 6 * 468) {
        int l = b / 468, t = b % 468;
        conv_layer_quad(t,
            Wr + (size_t)l * WSZ, Wk + (size_t)l * WSZ, Wv + (size_t)l * WSZ,
            Wg + (size_t)l * WSZ, Wo + (size_t)l * WSZ, Wcg + (size_t)l * WSZ,
            Win + (size_t)l * CDIM * FDIM, Wout + (size_t)l * FDIM * CDIM,
            wbuf + (size_t)l * WBUF_ELEMS);
    } else if (b < 6 * 468 + 2358) {
        int t = b - 6 * 468;               // unembed: 6 tkq x 393 tnp
        int tkq = t / 393, tnp = t % 393;
        trans_quad(unemb, ubuf, CDIM, VDIM, tkq, tnp);
    } else {
        embed_ln_row(b - (6 * 468 + 2358), tok, embed, eln, x);
    }
}

// ---------------- LayerNorm over C=768 -> bf16 (head input) ----------------
__global__ __launch_bounds__(256)
void k_ln_bf(const float* __restrict__ x, const float* __restrict__ wb,
             ushort* __restrict__ out) {
    int t = blockIdx.x, tid = threadIdx.x;
    float v[3]; float s = 0.f, s2 = 0.f;
    #pragma unroll
    for (int j = 0; j < 3; j++) {
        v[j] = x[(size_t)t * CDIM + tid + j * 256];
        s += v[j]; s2 += v[j] * v[j];
    }
    #pragma unroll
    for (int m = 32; m; m >>= 1) { s += __shfl_xor(s, m); s2 += __shfl_xor(s2, m); }
    __shared__ float rs[4], rq[4];
    int w = tid >> 6;
    if ((tid & 63) == 0) { rs[w] = s; rq[w] = s2; }
    __syncthreads();
    s = rs[0] + rs[1] + rs[2] + rs[3];
    s2 = rq[0] + rq[1] + rq[2] + rq[3];
    float mu = s * (1.f / CDIM);
    float inv = rsqrtf(s2 * (1.f / CDIM) - mu * mu + 1e-5f);
    #pragma unroll
    for (int j = 0; j < 3; j++) {
        int c = tid + j * 256;
        out[(size_t)t * CDIM + c] = f2bf((v[j] - mu) * inv * wb[c] + wb[CDIM + c]);
    }
}

// ---------------- fused LN + token-shift lerp -> NM bf16 mix buffers --------
template <int NM>
__global__ __launch_bounds__(256)
void k_lnlerp(const float* __restrict__ x, const float* __restrict__ lnw,
              const float* __restrict__ ts, ushort* __restrict__ mix) {
    int t = blockIdx.x, tid = threadIdx.x;
    bool has = (t > 0);
    float vb[3], va[3];
    float sb = 0.f, qb = 0.f, sa = 0.f, qa = 0.f;
    #pragma unroll
    for (int j = 0; j < 3; j++) {
        int c = tid + j * 256;
        vb[j] = x[(size_t)t * CDIM + c];
        sb += vb[j]; qb += vb[j] * vb[j];
        va[j] = has ? x[(size_t)(t - 1) * CDIM + c] : 0.f;
        sa += va[j]; qa += va[j] * va[j];
    }
    #pragma unroll
    for (int m = 32; m; m >>= 1) {
        sb += __shfl_xor(sb, m); qb += __shfl_xor(qb, m);
        sa += __shfl_xor(sa, m); qa += __shfl_xor(qa, m);
    }
    __shared__ float r0[4], r1[4], r2[4], r3[4];
    int w = tid >> 6;
    if ((tid & 63) == 0) { r0[w] = sb; r1[w] = qb; r2[w] = sa; r3[w] = qa; }
    __syncthreads();
    sb = r0[0] + r0[1] + r0[2] + r0[3]; qb = r1[0] + r1[1] + r1[2] + r1[3];
    sa = r2[0] + r2[1] + r2[2] + r2[3]; qa = r3[0] + r3[1] + r3[2] + r3[3];
    float mub = sb * (1.f / CDIM);
    float invb = rsqrtf(qb * (1.f / CDIM) - mub * mub + 1e-5f);
    float mua = sa * (1.f / CDIM);
    float inva = rsqrtf(qa * (1.f / CDIM) - mua * mua + 1e-5f);
    #pragma unroll
    for (int j = 0; j < 3; j++) {
        int c = tid + j * 256;
        float wgt = lnw[c], bia = lnw[CDIM + c];
        float xb = (vb[j] - mub) * invb * wgt + bia;
        float xa = has ? (va[j] - mua) * inva * wgt + bia : 0.f;
        #pragma unroll
        for (int m = 0; m < NM; m++) {
            float tv = ts[m * CDIM + c];
            mix[((size_t)m * T_LEN + t) * CDIM + c] = f2bf(xa + (xb - xa) * tv);
        }
    }
}

// ------- layer GEMM: A LDS-staged, B direct-from-global frag-order ----------
// EPI: 0=f32, 1=resid+f32, 2=relu^2->bf16, 3=resid+v*sigmoid(bf16 gate), 4=bf16
template <int BM, int BN, int EPI>
__device__ __forceinline__ void gemm_body(
        const ushort* __restrict__ A, const ushort* __restrict__ Bf,
        float* __restrict__ Cf, ushort* __restrict__ Cb,
        const float* __restrict__ resid, const ushort* __restrict__ gate,
        int N, int K, int mb, int nb, ushort* Al) {
    const int tid = threadIdx.x, lane = tid & 63, wave = tid >> 6;
    constexpr int WM = BM / 2, WN = BN / 2, FM = WM / 16, FN = WN / 16;
    const int wm = (wave >> 1) * WM, wn = (wave & 1) * WN;
    constexpr int AR = BM / 32;          // 16B A-slots per thread per k-tile
    constexpr int LD = AR + 2 * FN;      // vmem ops per k-tile per thread
    const int kq = lane >> 4, ln15 = lane & 15;

    const size_t bstride = (size_t)(K >> 6) * 2048;   // bytes per n16 tile-row
    const char* bbase = (const char*)Bf +
        (size_t)((nb + wn) >> 4) * bstride + lane * 16;

    auto stageA = [&](int buf, int kt) {
        int k0 = kt << 6;
        #pragma unroll
        for (int r = 0; r < AR; r++) {
            int slot = tid + r * 256;
            int row = slot >> 3, g = slot & 7;
            int gk = ((g ^ (row & 7)) << 3);
            gload_lds16(A + (size_t)(mb + row) * K + k0 + gk,
                        &Al[buf * BM * 64 + slot * 8]);
        }
    };
    auto loadB = [&](s16x8 (&dst)[2][FN], int kt) {
        const char* p = bbase + (size_t)kt * 2048;
        #pragma unroll
        for (int s = 0; s < 2; s++)
            #pragma unroll
            for (int j = 0; j < FN; j++)
                dst[s][j] = *(const s16x8*)(p + (size_t)j * bstride + s * 1024);
    };

    f32x4 acc[FM][FN];
    #pragma unroll
    for (int i = 0; i < FM; i++)
        #pragma unroll
        for (int j = 0; j < FN; j++) acc[i][j] = (f32x4)0.f;

    auto compute = [&](const ushort* Ab, s16x8 (&bfr)[2][FN]) {
        #pragma unroll
        for (int s = 0; s < 2; s++) {
            s16x8 af[FM];
            #pragma unroll
            for (int i = 0; i < FM; i++) {
                int row = wm + i * 16 + ln15;
                int g = (s * 4 + kq) ^ (row & 7);
                af[i] = *(const s16x8*)&Ab[row * 64 + g * 8];
            }
            #pragma unroll
            for (int i = 0; i < FM; i++)
                #pragma unroll
                for (int j = 0; j < FN; j++)
                    acc[i][j] = __builtin_amdgcn_mfma_f32_16x16x32_bf16(
                        af[i], bfr[s][j], acc[i][j], 0, 0, 0);
        }
    };

    const int nt = K >> 6;               // even (12 or 42) at every call site
    s16x8 b0[2][FN], b1[2][FN];
    stageA(0, 0); loadB(b0, 0);
    stageA(1, 1); loadB(b1, 1);
    for (int t = 0; t < nt; t += 2) {
        wait_vm<LD>();                   // tile t done; tile t+1 in flight
        barrier_asm();
        compute(Al, b0);
        barrier_asm();
        if (t + 2 < nt) { stageA(0, t + 2); loadB(b0, t + 2); }
        if (t + 2 < nt) wait_vm<LD>();   // tile t+1 done; tile t+2 in flight
        else            wait_vm<0>();
        barrier_asm();
        compute(Al + BM * 64, b1);
        barrier_asm();
        if (t + 3 < nt) { stageA(1, t + 3); loadB(b1, t + 3); }
    }
    #pragma unroll
    for (int i = 0; i < FM; i++) {
        int rbase = mb + wm + i * 16 + (lane >> 4) * 4;
        #pragma unroll
        for (int j = 0; j < FN; j++) {
            int col = nb + wn + j * 16 + (lane & 15);
            #pragma unroll
            for (int r = 0; r < 4; r++) {
                size_t idx = (size_t)(rbase + r) * N + col;
                float vv = acc[i][j][r];
                if constexpr (EPI == 0) {
                    Cf[idx] = vv;
                } else if constexpr (EPI == 1) {
                    Cf[idx] = resid[idx] + vv;
                } else if constexpr (EPI == 2) {
                    float z = vv > 0.f ? vv * vv : 0.f;
                    Cb[idx] = f2bf(z);
                } else if constexpr (EPI == 3) {
                    float gv = bf2f(gate[idx]);
                    Cf[idx] = resid[idx] + vv / (1.f + __expf(-gv));
                } else {
                    Cb[idx] = f2bf(vv);
                }
            }
        }
    }
}

template <int BM, int BN, int EPI, bool BATCH>
__global__ __launch_bounds__(256)
void k_gemm_std(const ushort* __restrict__ A, const ushort* __restrict__ Bf,
                float* __restrict__ Cf, ushort* __restrict__ Cb,
                const float* __restrict__ resid, const ushort* __restrict__ gate,
                int N, int K) {
    __shared__ __align__(16) ushort Al[2 * BM * 64];
    if constexpr (BATCH) {
        int z = blockIdx.z;
        A  += (size_t)z * T_LEN * CDIM;
        Bf += (size_t)z * CDIM * CDIM;
        if constexpr (EPI == 4) Cb += (size_t)z * T_LEN * CDIM;
        else                    Cf += (size_t)z * T_LEN * CDIM;
    }
    gemm_body<BM, BN, EPI>(A, Bf, Cf, Cb, resid, gate, N, K,
                           blockIdx.y * BM, blockIdx.x * BN, Al);
}

// ------- head GEMM: BOTH operands LDS-staged (proven fastest for head) ------
__global__ __launch_bounds__(256)
void k_gemm_head(const ushort* __restrict__ A, const ushort* __restrict__ Bf,
                 float* __restrict__ C) {
    __shared__ __align__(16) ushort Al[2 * 128 * 64];
    __shared__ __align__(16) ushort Bl[2 * 128 * 64];
    int id = blockIdx.x;
    int xcd = id & 7, slot = id >> 3;
    int mbi = slot & 7, nbl = slot >> 3;
    int nbi = nbl * 8 + xcd;                 // bijective, balanced
    if (nbi >= VDIM / 128) return;
    const int mb = mbi * 128, nb = nbi * 128;
    const int tid = threadIdx.x, lane = tid & 63, wave = tid >> 6;
    const int wm = (wave >> 1) * 64, wn = (wave & 1) * 64;
    const int kq = lane >> 4, ln15 = lane & 15;
    constexpr int K = CDIM, N = VDIM;
    const size_t bstride = (size_t)(K >> 6) * 1024;   // ushorts per n16 row

    auto stage = [&](int buf, int kt) {
        int k0 = kt << 6;
        #pragma unroll
        for (int r = 0; r < 4; r++) {
            int slot2 = tid + r * 256;
            int row = slot2 >> 3, g = slot2 & 7;
            int gk = ((g ^ (row & 7)) << 3);
            gload_lds16(A + (size_t)(mb + row) * K + k0 + gk,
                        &Al[buf * 8192 + slot2 * 8]);
        }
        #pragma unroll
        for (int r = 0; r < 4; r++) {
            int slot2 = tid + r * 256;          // 1024 slots x 16B = 16KB
            int n16 = slot2 >> 7, off = slot2 & 127;
            gload_lds16(Bf + (size_t)((nb >> 4) + n16) * bstride
                           + (size_t)kt * 1024 + off * 8,
                        &Bl[buf * 8192 + slot2 * 8]);
        }
    };

    f32x4 acc[4][4];
    #pragma unroll
    for (int i = 0; i < 4; i++)
        #pragma unroll
        for (int j = 0; j < 4; j++) acc[i][j] = (f32x4)0.f;

    stage(0, 0);
    stage(1, 1);
    for (int t = 0; t < 12; t++) {
        if (t < 11) wait_vm<8>();
        else        wait_vm<0>();
        barrier_asm();
        const ushort* Ab = &Al[(t & 1) * 8192];
        #pragma unroll
        for (int s = 0; s < 2; s++) {
            s16x8 af[4], bfr[4];
            #pragma unroll
            for (int i = 0; i < 4; i++) {
                int row = wm + i * 16 + ln15;
                int g = (s * 4 + kq) ^ (row & 7);
                af[i] = *(const s16x8*)&Ab[row * 64 + g * 8];
            }
            #pragma unroll
            for (int j = 0; j < 4; j++) {
                int n16 = (wn >> 4) + j;
                bfr[j] = *(const s16x8*)&Bl[(t & 1) * 8192 + n16 * 1024
                                            + (s * 512) + lane * 8];
            }
            #pragma unroll
            for (int i = 0; i < 4; i++)
                #pragma unroll
                for (int j = 0; j < 4; j++)
                    acc[i][j] = __builtin_amdgcn_mfma_f32_16x16x32_bf16(
                        af[i], bfr[j], acc[i][j], 0, 0, 0);
        }
        barrier_asm();
        if (t + 2 < 12) stage(t & 1, t + 2);
    }
    #pragma unroll
    for (int i = 0; i < 4; i++) {
        int rbase = mb + wm + i * 16 + (lane >> 4) * 4;
        #pragma unroll
        for (int j = 0; j < 4; j++) {
            int col = nb + wn + j * 16 + ln15;
            #pragma unroll
            for (int r = 0; r < 4; r++)
                C[(size_t)(rbase + r) * N + col] = acc[i][j][r];
        }
    }
}

// channel-mixer Win (relu^2 -> hb) + Wcg (bf16 gcm) merged, 128x64 tiles
__global__ __launch_bounds__(256)
void k_cmix(const ushort* __restrict__ mix, const ushort* __restrict__ wl,
            ushort* __restrict__ hb, ushort* __restrict__ gcm) {
    __shared__ __align__(16) ushort Al[2 * 128 * 64];
    int bx = blockIdx.x, mb = blockIdx.y * 128;
    if (bx < FDIM / 64) {
        gemm_body<128, 64, 2>(mix, wl + WIN_OFF, nullptr, hb, nullptr, nullptr,
                              FDIM, CDIM, mb, bx * 64, Al);
    } else {
        gemm_body<128, 64, 4>(mix + (size_t)T_LEN * CDIM, wl + 5 * WSZ, nullptr,
                              gcm, nullptr, nullptr, CDIM, CDIM, mb,
                              (bx - FDIM / 64) * 64, Al);
    }
}

// ---------------- WKV chunked scan (bf16 r/k/v/gate inputs) -----------------
__global__ __launch_bounds__(256)
void k_wkv1(const ushort* __restrict__ kb, const ushort* __restrict__ vb,
            const float* __restrict__ decay, float* __restrict__ Stil) {
    int c = blockIdx.x / HNUM, h = blockIdx.x % HNUM;
    __shared__ float kl[4096], vl[4096], wsh[64];
    int tid = threadIdx.x;
    for (int idx = tid; idx < 512; idx += 256) {      // 512 x ushort8
        int j = idx >> 3, c8 = (idx & 7) * 8;
        size_t g = (size_t)(c * LCH + j) * CDIM + h * 64 + c8;
        s16x8 ku = *(const s16x8*)&kb[g];
        s16x8 vu = *(const s16x8*)&vb[g];
        #pragma unroll
        for (int e = 0; e < 8; e++) {
            kl[j * 64 + c8 + e] = bf2f((ushort)ku[e]);
            vl[j * 64 + c8 + e] = bf2f((ushort)vu[e]);
        }
    }
    if (tid < 64) wsh[tid] = expf(-expf(decay[h * 64 + tid]));
    __syncthreads();
    int k = tid >> 2, v0 = (tid & 3) * 16;
    float w = wsh[k], f = 1.f;
    float s[16];
    #pragma unroll
    for (int i = 0; i < 16; i++) s[i] = 0.f;
    for (int j = 63; j >= 0; --j) {
        float kw = kl[j * 64 + k] * f;
        #pragma unroll
        for (int i = 0; i < 16; i++) s[i] += kw * vl[j * 64 + v0 + i];
        f *= w;
    }
    float* dst = Stil + ((size_t)(c * HNUM + h) << 12) + k * 64 + v0;
    #pragma unroll
    for (int i = 0; i < 16; i++) dst[i] = s[i];
}

// pass2+3 merged + fused GroupNorm*silu(gate) -> bf16 y
__global__ __launch_bounds__(256)
void k_wkv23(const ushort* __restrict__ rb, const ushort* __restrict__ kb,
             const ushort* __restrict__ vb, const float* __restrict__ Stil,
             const float* __restrict__ decay, const float* __restrict__ bonus,
             const ushort* __restrict__ gate, const float* __restrict__ gnw,
             ushort* __restrict__ y) {
    int c = blockIdx.x / HNUM, h = blockIdx.x % HNUM;
    __shared__ float rl[4096], kl[4096], vl[4096];
    __shared__ float part[4][4096];
    __shared__ float wsh[64], bsh[64];
    int tid = threadIdx.x;
    for (int idx = tid; idx < 512; idx += 256) {      // 512 x ushort8
        int j = idx >> 3, c8 = (idx & 7) * 8;
        size_t g = (size_t)(c * LCH + j) * CDIM + h * 64 + c8;
        s16x8 ru = *(const s16x8*)&rb[g];
        s16x8 ku = *(const s16x8*)&kb[g];
        s16x8 vu = *(const s16x8*)&vb[g];
        #pragma unroll
        for (int e = 0; e < 8; e++) {
            rl[j * 64 + c8 + e] = bf2f((ushort)ru[e]);
            kl[j * 64 + c8 + e] = bf2f((ushort)ku[e]);
            vl[j * 64 + c8 + e] = bf2f((ushort)vu[e]);
        }
    }
    if (tid < 64) {
        wsh[tid] = expf(-expf(decay[h * 64 + tid]));
        bsh[tid] = bonus[h * 64 + tid];
    }
    __syncthreads();
    int v = tid & 63, kg = tid >> 6;
    float S[16], wr[16], br[16], w64[16];
    #pragma unroll
    for (int i = 0; i < 16; i++) {
        S[i] = 0.f;
        wr[i] = wsh[kg * 16 + i];
        br[i] = bsh[kg * 16 + i];
        float t2 = wr[i];
        t2 *= t2; t2 *= t2; t2 *= t2; t2 *= t2; t2 *= t2; t2 *= t2;  // w^64
        w64[i] = t2;
    }
    for (int cc = 0; cc < c; cc++) {                 // chunk-prefix stitch
        const float* sp = Stil + ((size_t)(cc * HNUM + h) << 12);
        #pragma unroll
        for (int i = 0; i < 16; i++)
            S[i] = S[i] * w64[i] + sp[(kg * 16 + i) * 64 + v];
    }
    for (int j = 0; j < 64; j++) {
        float vj = vl[j * 64 + v];
        const float4* kp = (const float4*)&kl[j * 64 + kg * 16];
        const float4* rp = (const float4*)&rl[j * 64 + kg * 16];
        float rsum = 0.f;
        #pragma unroll
        for (int qq = 0; qq < 4; qq++) {
            float4 k4 = kp[qq], r4 = rp[qq];
            const float* kf = (const float*)&k4;
            const float* rf = (const float*)&r4;
            #pragma unroll
            for (int e = 0; e < 4; e++) {
                int i = qq * 4 + e;
                float a = kf[e] * vj;
                rsum += rf[e] * (S[i] + a * br[i]);
                S[i] = S[i] * wr[i] + a;
            }
        }
        part[kg][j * 64 + v] = rsum;
    }
    __syncthreads();
    for (int jj = 0; jj < 16; jj++) {
        int j = kg * 16 + jj;
        float o = part[0][j * 64 + v] + part[1][j * 64 + v] +
                  part[2][j * 64 + v] + part[3][j * 64 + v];
        float s = o, s2 = o * o;
        #pragma unroll
        for (int m = 32; m; m >>= 1) { s += __shfl_xor(s, m); s2 += __shfl_xor(s2, m); }
        float mu = s * (1.f / 64.f);
        float var = s2 * (1.f / 64.f) - mu * mu;
        float xg = (o - mu) * rsqrtf(var + 6.4e-4f);
        int t = c * LCH + j, col = h * 64 + v;
        float gv = bf2f(gate[(size_t)t * CDIM + col]);
        float silu = gv / (1.f + __expf(-gv));
        y[(size_t)t * CDIM + col] = f2bf((xg * gnw[col] + gnw[CDIM + col]) * silu);
    }
}

// ---------------- host ----------------
extern "C" void kernel_launch(void* const* d_in, const int* in_sizes, int n_in,
                              void* d_out, int out_size, void* d_ws, size_t ws_size,
                              hipStream_t stream) {
    const int*   tok      = (const int*)d_in[0];
    const float* embed    = (const float*)d_in[1];
    const float* embed_ln = (const float*)d_in[2];
    const float* tm_ln    = (const float*)d_in[3];
    const float* tm_ts    = (const float*)d_in[4];
    const float* tm_Wr    = (const float*)d_in[5];
    const float* tm_Wk    = (const float*)d_in[6];
    const float* tm_Wv    = (const float*)d_in[7];
    const float* tm_Wg    = (const float*)d_in[8];
    const float* tm_Wo    = (const float*)d_in[9];
    const float* tm_bonus = (const float*)d_in[10];
    const float* tm_decay = (const float*)d_in[11];
    const float* tm_gn    = (const float*)d_in[12];
    const float* cm_ln    = (const float*)d_in[13];
    const float* cm_ts    = (const float*)d_in[14];
    const float* cm_Win   = (const float*)d_in[15];
    const float* cm_Wout  = (const float*)d_in[16];
    const float* cm_Wg    = (const float*)d_in[17];
    const float* head_ln  = (const float*)d_in[18];
    const float* unembed  = (const float*)d_in[19];
    float* out = (float*)d_out;

    const size_t TC = (size_t)T_LEN * CDIM;
    char* wp = (char*)d_ws;
    auto alloc = [&](size_t bytes) {
        char* p = wp; wp += (bytes + 255) & ~(size_t)255; return p;
    };
    float*  x    = (float*)alloc(TC * 4);
    ushort* mix  = (ushort*)alloc(4 * TC * 2);
    ushort* rkvg = (ushort*)alloc(4 * TC * 2);
    ushort* gcm  = (ushort*)alloc(TC * 2);
    ushort* y    = (ushort*)alloc(TC * 2);
    ushort* hb   = (ushort*)alloc((size_t)T_LEN * FDIM * 2);
    float*  Stil = (float*)alloc((size_t)NCH * HNUM * 4096 * 4);
    ushort* ubuf = (ushort*)alloc((size_t)CDIM * VDIM * 2);
    size_t fixed_bytes = (size_t)(wp - (char*)d_ws);
    const size_t per_layer = ((size_t)WBUF_ELEMS * 2 + 255) & ~(size_t)255;
    bool all6 = (fixed_bytes + 6 * per_layer) <= ws_size;
    ushort* wbuf = (ushort*)alloc(all6 ? 6 * per_layer : per_layer);
    if ((size_t)(wp - (char*)d_ws) > ws_size) return;   // fail loudly, no UB

    if (all6) {
        k_conv_all<<<6 * 468 + 2358 + 1024, 256, 0, stream>>>(
            tm_Wr, tm_Wk, tm_Wv, tm_Wg, tm_Wo, cm_Wg, cm_Win, cm_Wout,
            unembed, wbuf, ubuf, tok, embed, embed_ln, x);
    } else {
        k_trans<<<dim3(VDIM / 64, CDIM / 64), 256, 0, stream>>>(
            unembed, ubuf, CDIM, VDIM);
        k_embed_ln<<<T_LEN, 256, 0, stream>>>(tok, embed, embed_ln, x);
    }

    dim3 g64(CDIM / 64, T_LEN / 64);        // (12,16)
    dim3 gQKVG(CDIM / 64, T_LEN / 128, 4);  // (12,8,4) 128x64 tiles
    dim3 gCmix(FDIM / 64 + CDIM / 64, T_LEN / 128);  // (54,8) 128x64 tiles

    for (int l = 0; l < LNUM; l++) {
        ushort* wl = all6 ? (ushort*)((char*)wbuf + (size_t)l * per_layer) : wbuf;
        if (!all6) {
            const size_t lo = (size_t)l * CDIM * CDIM;
            k_conv_layer<<<1872, 256, 0, stream>>>(
                tm_Wr + lo, tm_Wk + lo, tm_Wv + lo, tm_Wg + lo, tm_Wo + lo,
                cm_Wg + lo, cm_Win + (size_t)l * CDIM * FDIM,
                cm_Wout + (size_t)l * FDIM * CDIM, wl);
        }
        const float* dec = tm_decay + (size_t)l * HNUM * KDIM;
        const float* bon = tm_bonus + (size_t)l * HNUM * KDIM;

        // ---- time mixer ----
        k_lnlerp<4><<<T_LEN, 256, 0, stream>>>(x, tm_ln + (size_t)l * 2 * CDIM,
                                               tm_ts + (size_t)l * 4 * CDIM, mix);
        k_gemm_std<128,64,4,true><<<gQKVG, 256, 0, stream>>>(
            mix, wl, nullptr, rkvg, nullptr, nullptr, CDIM, CDIM);
        k_wkv1<<<NCH * HNUM, 256, 0, stream>>>(rkvg + TC, rkvg + 2 * TC, dec, Stil);
        k_wkv23<<<NCH * HNUM, 256, 0, stream>>>(rkvg, rkvg + TC, rkvg + 2 * TC,
            Stil, dec, bon, rkvg + 3 * TC, tm_gn + (size_t)l * 2 * CDIM, y);
        k_gemm_std<64,64,1,false><<<g64, 256, 0, stream>>>(
            y, wl + 4 * WSZ, x, nullptr, x, nullptr, CDIM, CDIM);

        // ---- channel mixer ----
        k_lnlerp<2><<<T_LEN, 256, 0, stream>>>(x, cm_ln + (size_t)l * 2 * CDIM,
                                               cm_ts + (size_t)l * 2 * CDIM, mix);
        k_cmix<<<gCmix, 256, 0, stream>>>(mix, wl, hb, gcm);
        k_gemm_std<64,64,3,false><<<g64, 256, 0, stream>>>(
            hb, wl + WOUT_OFF, x, nullptr, x, gcm, CDIM, FDIM);
    }

    k_ln_bf<<<T_LEN, 256, 0, stream>>>(x, head_ln, mix);
    k_gemm_head<<<3200, 256, 0, stream>>>(mix, ubuf, out);
}